// Round 12
// baseline (442.041 us; speedup 1.0000x reference)
//
#include <hip/hip_runtime.h>
#include <hip/hip_bf16.h>
#include <cstdint>
#include <cstddef>

// ---------------- problem constants ----------------
#define BB 4
#define LL 4096
#define DD 768
#define KK 12
#define HH 64
#define KSZ 4
#define DIM_MEM 768
#define DIM_MEMT 780
#define DIM_Q 768
#define DIM_CONV 1548
#define DIM_SKIP 192
#define DIM_SWH 384
#define DIM_TOTAL 1752
#define TTOK (BB*LL)
#define NCHUNK 128
#define LCHUNK 32            // LL / NCHUNK
#define N1REAL 1752
#define N1PAD 1792
#define DGATE (KK*2*HH)      // 1536

typedef unsigned short ushort_t;
typedef __attribute__((ext_vector_type(8))) short short8v;   // 8 x bf16 (4 VGPRs)
typedef __attribute__((ext_vector_type(4))) float f32x4;

// ---------------- helpers ----------------
// fast sigmoid: v_exp + v_rcp (rel err ~1e-6, far below bf16 noise)
__device__ __forceinline__ float sigm(float x) {
    return __builtin_amdgcn_rcpf(1.0f + __expf(-x));
}
// fast softplus; absolute error at tiny outputs is masked by the dt>=0.001 clamp
__device__ __forceinline__ float softplus_fast(float x) {
    return (x > 0.f) ? (x + __logf(1.0f + __expf(-x))) : __logf(1.0f + __expf(x));
}
__device__ __forceinline__ ushort_t f2bf(float f) {
    __hip_bfloat16 h = __float2bfloat16(f);
    return __builtin_bit_cast(ushort_t, h);
}
__device__ __forceinline__ float bf2f(ushort_t u) {
    const uint32_t i = ((uint32_t)u) << 16;
    return __builtin_bit_cast(float, i);
}
__device__ __forceinline__ float waveReduceSum(float v) {
    #pragma unroll
    for (int off = 32; off > 0; off >>= 1) v += __shfl_xor(v, off);
    return v;
}
__device__ __forceinline__ void gload_lds16(const void* g, void* l) {
    __builtin_amdgcn_global_load_lds(
        (const __attribute__((address_space(1))) void*)g,
        (__attribute__((address_space(3))) void*)l, 16, 0, 0);
}

// ---------------- cast fp32 -> bf16 (vectorized) ----------------
__launch_bounds__(256)
__global__ void cast_bf16(const float* __restrict__ in, ushort_t* __restrict__ out, int n4) {
    const int stride = gridDim.x * 256;
    for (int i = blockIdx.x * 256 + threadIdx.x; i < n4; i += stride) {
        const float4 v = reinterpret_cast<const float4*>(in)[i];
        ushort4 o;
        o.x = f2bf(v.x); o.y = f2bf(v.y); o.z = f2bf(v.z); o.w = f2bf(v.w);
        reinterpret_cast<ushort4*>(out)[i] = o;
    }
}

// ---------------- transpose + cast: in[R][Cc] f32 -> out[Cpad][R] bf16 (zero pad) ----------------
__global__ void transpose_cast(const float* __restrict__ in, ushort_t* __restrict__ out,
                               int R, int Cc, int Cpad) {
    __shared__ float tile[32][33];
    const int tx = threadIdx.x, ty = threadIdx.y;
    const int c0 = blockIdx.x * 32, r0 = blockIdx.y * 32;
    #pragma unroll
    for (int rr = ty; rr < 32; rr += 8) {
        const int r = r0 + rr, c = c0 + tx;
        tile[rr][tx] = (r < R && c < Cc) ? in[(size_t)r * Cc + c] : 0.f;
    }
    __syncthreads();
    #pragma unroll
    for (int rr = ty; rr < 32; rr += 8) {
        const int c = c0 + rr, r = r0 + tx;
        if (c < Cpad && r < R)
            out[(size_t)c * R + r] = f2bf(tile[tx][rr]);
    }
}

// ---------------- build Bt for gemm2: Btv/Btg [12][192][320] bf16 ----------------
__global__ void prep_bt(const float* __restrict__ Wr, const float* __restrict__ Wskip,
                        ushort_t* __restrict__ Btv, ushort_t* __restrict__ Btg) {
    const int k = blockIdx.x, n = blockIdx.y, kk = threadIdx.x;   // block 320
    float v, g;
    if (kk < 128) {
        const size_t base = ((size_t)k * 128 + kk) * DIM_SWH;
        v = Wr[base + n];
        g = Wr[base + 192 + n];
    } else {
        const size_t base = (size_t)(kk - 128) * (KK * DIM_SWH) + (size_t)k * DIM_SWH;
        v = Wskip[base + n];
        g = Wskip[base + 192 + n];
    }
    const size_t o = ((size_t)k * 192 + n) * 320 + kk;
    Btv[o] = f2bf(v);
    Btg[o] = f2bf(g);
}

// ---------------- prep wint: wint[768] = exp(clamp(w_int_raw, -5, 5))  (accurate, runs once) ----------------
__global__ void prep_wint(const float* __restrict__ w_int_raw, float* __restrict__ wint) {
    const int i = blockIdx.x * 256 + threadIdx.x;
    if (i < KK * HH) {
        float wr = w_int_raw[i];
        wr = fminf(fmaxf(wr, -5.f), 5.f);
        wint[i] = expf(wr);
    }
}

// ---------------- bf16 MFMA GEMM (BK=32, 5 blocks/CU): C[M,Nreal] = A @ Bt^T ----------------
template <bool BF16OUT>
__launch_bounds__(256)
__global__ void mfma_gemm(const ushort_t* __restrict__ A, const ushort_t* __restrict__ Bt,
                          void* __restrict__ Cv, int Nreal, int K) {
    __shared__ ushort_t As[2][128 * 32];
    __shared__ ushort_t Bs[2][128 * 32];
    const int tid = threadIdx.x;
    const int lane = tid & 63, w = tid >> 6;
    const int m0 = blockIdx.x * 128, n0 = blockIdx.y * 128;
    const int wm = w & 1, wn = w >> 1;
    const int nkt = K >> 5;
    const int lrow = lane >> 2;          // 0..15
    const int lcol = (lane & 3) * 8;     // 0,8,16,24

    f32x4 acc[4][4] = {};

    auto stage = [&](int buf, int k0) {
        #pragma unroll
        for (int i = 0; i < 2; ++i) {
            const int seg = w * 2 + i;               // 0..7 (16 rows each)
            const int row = seg * 16 + lrow;
            gload_lds16(&A[(size_t)(m0 + row) * K + k0 + lcol], &As[buf][seg * 512]);
            gload_lds16(&Bt[(size_t)(n0 + row) * K + k0 + lcol], &Bs[buf][seg * 512]);
        }
    };

    stage(0, 0);
    for (int kt = 0; kt < nkt; ++kt) {
        const int cur = kt & 1;
        __syncthreads();
        if (kt + 1 < nkt) stage(cur ^ 1, (kt + 1) << 5);
        short8v a[4], b[4];
        #pragma unroll
        for (int i = 0; i < 4; ++i)
            a[i] = *(const short8v*)&As[cur][(wm * 64 + i * 16 + (lane & 15)) * 32 + (lane >> 4) * 8];
        #pragma unroll
        for (int j = 0; j < 4; ++j)
            b[j] = *(const short8v*)&Bs[cur][(wn * 64 + j * 16 + (lane & 15)) * 32 + (lane >> 4) * 8];
        #pragma unroll
        for (int i = 0; i < 4; ++i)
            #pragma unroll
            for (int j = 0; j < 4; ++j)
                acc[i][j] = __builtin_amdgcn_mfma_f32_16x16x32_bf16(a[i], b[j], acc[i][j], 0, 0, 0);
    }
    #pragma unroll
    for (int i = 0; i < 4; ++i) {
        const int rbase = m0 + wm * 64 + i * 16 + (lane >> 4) * 4;
        #pragma unroll
        for (int j = 0; j < 4; ++j) {
            const int col = n0 + wn * 64 + j * 16 + (lane & 15);
            if (col < Nreal) {
                #pragma unroll
                for (int r = 0; r < 4; ++r) {
                    if constexpr (BF16OUT)
                        ((ushort_t*)Cv)[(size_t)(rbase + r) * Nreal + col] = f2bf(acc[i][j][r]);
                    else
                        ((float*)Cv)[(size_t)(rbase + r) * Nreal + col] = acc[i][j][r];
                }
            }
        }
    }
}

// ---------------- gemm2 MFMA: per-k grouped GEMM with fused val*silu(gate) ----------------
__launch_bounds__(256)
__global__ void gemm2_mfma(const ushort_t* __restrict__ OCNb, const ushort_t* __restrict__ CskB,
                           const ushort_t* __restrict__ Btv, const ushort_t* __restrict__ Btg,
                           ushort_t* __restrict__ Y) {
    __shared__ ushort_t As[2][128 * 64];
    __shared__ ushort_t Bvs[2][64 * 64];
    __shared__ ushort_t Bgs[2][64 * 64];
    const int tid = threadIdx.x;
    const int lane = tid & 63, w = tid >> 6;
    const int m0 = blockIdx.x * 128;
    const int n0 = blockIdx.y * 64;
    const int k  = blockIdx.z;
    const int wm = w & 1, wn = w >> 1;
    const int lrow = lane >> 3;
    const int lcol = (lane & 7) * 8;
    const ushort_t* btv = Btv + (size_t)k * 192 * 320;
    const ushort_t* btg = Btg + (size_t)k * 192 * 320;

    f32x4 accV[4][2] = {};
    f32x4 accG[4][2] = {};

    auto stage = [&](int buf, int kt) {
        #pragma unroll
        for (int i = 0; i < 4; ++i) {
            const int seg = w * 4 + i;
            const int row = seg * 8 + lrow;
            const ushort_t* src = (kt < 2)
                ? OCNb + (size_t)(m0 + row) * DGATE + k * 128 + kt * 64 + lcol
                : CskB + (size_t)(m0 + row) * DIM_SKIP + (kt - 2) * 64 + lcol;
            gload_lds16(src, &As[buf][seg * 512]);
        }
        #pragma unroll
        for (int i = 0; i < 2; ++i) {
            const int seg = w * 2 + i;
            const int row = seg * 8 + lrow;
            gload_lds16(btv + (size_t)(n0 + row) * 320 + kt * 64 + lcol, &Bvs[buf][seg * 512]);
            gload_lds16(btg + (size_t)(n0 + row) * 320 + kt * 64 + lcol, &Bgs[buf][seg * 512]);
        }
    };

    stage(0, 0);
    for (int kt = 0; kt < 5; ++kt) {
        const int cur = kt & 1;
        __syncthreads();
        if (kt + 1 < 5) stage(cur ^ 1, kt + 1);
        #pragma unroll
        for (int kk = 0; kk < 2; ++kk) {
            short8v a[4], bv[2], bg[2];
            #pragma unroll
            for (int i = 0; i < 4; ++i)
                a[i] = *(const short8v*)&As[cur][(wm * 64 + i * 16 + (lane & 15)) * 64 + kk * 32 + (lane >> 4) * 8];
            #pragma unroll
            for (int j = 0; j < 2; ++j) {
                bv[j] = *(const short8v*)&Bvs[cur][(wn * 32 + j * 16 + (lane & 15)) * 64 + kk * 32 + (lane >> 4) * 8];
                bg[j] = *(const short8v*)&Bgs[cur][(wn * 32 + j * 16 + (lane & 15)) * 64 + kk * 32 + (lane >> 4) * 8];
            }
            #pragma unroll
            for (int i = 0; i < 4; ++i)
                #pragma unroll
                for (int j = 0; j < 2; ++j) {
                    accV[i][j] = __builtin_amdgcn_mfma_f32_16x16x32_bf16(a[i], bv[j], accV[i][j], 0, 0, 0);
                    accG[i][j] = __builtin_amdgcn_mfma_f32_16x16x32_bf16(a[i], bg[j], accG[i][j], 0, 0, 0);
                }
        }
    }
    #pragma unroll
    for (int i = 0; i < 4; ++i) {
        const int rbase = m0 + wm * 64 + i * 16 + (lane >> 4) * 4;
        #pragma unroll
        for (int j = 0; j < 2; ++j) {
            const int col = k * 192 + n0 + wn * 32 + j * 16 + (lane & 15);
            #pragma unroll
            for (int r = 0; r < 4; ++r) {
                const float g = accG[i][j][r];
                Y[(size_t)(rbase + r) * (KK * 3 * HH) + col] = f2bf(accV[i][j][r] * (g * sigm(g)));
            }
        }
    }
}

// ---------------- fused feature + scan: per (b,k,chunk32), 64 lanes = 64 heads ----------------
__launch_bounds__(64)
__global__ void feat_scan(const ushort_t* __restrict__ Zb, const float* __restrict__ conv_w,
                          const float* __restrict__ wk, const float* __restrict__ theta_raw,
                          const float* __restrict__ dt_scale, const float* __restrict__ dt_bias,
                          const float* __restrict__ log_A, const float* __restrict__ phase_scale,
                          float2* __restrict__ acc, float* __restrict__ pcum,
                          float2* __restrict__ cend, float* __restrict__ cp) {
    const int blk = blockIdx.x;                  // (b*KK+k)*NCHUNK + chunk
    const int bk = blk / NCHUNK, chunk = blk - bk * NCHUNK;
    const int b = bk / KK, k = bk - b * KK;
    const int h = threadIdx.x;
    const int t0 = chunk * LCHUNK;
    const int cm_ch = k * HH + h;
    const int cs_ch = DIM_MEM + k;

    const float w0 = conv_w[0 * DIM_CONV + cm_ch];
    const float w1 = conv_w[1 * DIM_CONV + cm_ch];
    const float w2 = conv_w[2 * DIM_CONV + cm_ch];
    const float w3 = conv_w[3 * DIM_CONV + cm_ch];
    const float s0 = conv_w[0 * DIM_CONV + cs_ch];
    const float s1 = conv_w[1 * DIM_CONV + cs_ch];
    const float s2 = conv_w[2 * DIM_CONV + cs_ch];
    const float s3 = conv_w[3 * DIM_CONV + cs_ch];
    const float wkh = wk[h];
    const float th = 0.001f + (3.0f - 0.001f) * sigm(theta_raw[cm_ch]);
    const float ps = phase_scale[k];
    const float dts = dt_scale[k], dtb = dt_bias[k];
    const float eA = expf(log_A[k]);

    const size_t rowb = (size_t)b * LL;
    auto zm_at = [&](int t) -> float {
        return (t >= 0) ? bf2f(Zb[(rowb + t) * DIM_TOTAL + cm_ch]) : 0.f;
    };
    auto zs_at = [&](int t) -> float {
        return (t >= 0) ? bf2f(Zb[(rowb + t) * DIM_TOTAL + cs_ch]) : 0.f;
    };
    float zm3 = zm_at(t0 - 3), zm2 = zm_at(t0 - 2), zm1 = zm_at(t0 - 1);
    float zs3 = zs_at(t0 - 3), zs2 = zs_at(t0 - 2), zs1 = zs_at(t0 - 1);

    float are = 0.f, aim = 0.f, P = 1.f;
    // 4-way unroll: only the 2-FMA scan update is serially dependent.
    #pragma unroll 4
    for (int tt = 0; tt < LCHUNK; ++tt) {
        const int t = t0 + tt;
        const float zm0 = bf2f(Zb[(rowb + t) * DIM_TOTAL + cm_ch]);
        const float zs0 = bf2f(Zb[(rowb + t) * DIM_TOTAL + cs_ch]);
        float cm = fmaf(w0, zm3, fmaf(w1, zm2, fmaf(w2, zm1, w3 * zm0)));
        float cs = fmaf(s0, zs3, fmaf(s1, zs2, fmaf(s2, zs1, s3 * zs0)));
        const float um = cm * sigm(cm);
        const float us = cs * sigm(cs);
        float ssq = um * um;
        #pragma unroll
        for (int off = 32; off > 0; off >>= 1) ssq += __shfl_xor(ssq, off);
        const float kval = um * rsqrtf(ssq * (1.0f / (float)HH) + 1e-6f) * wkh;
        float lin = fminf(fmaxf(fmaf(dts, us, dtb), -20.f), 20.f);
        float dt = fminf(fmaxf(softplus_fast(lin), 0.001f), 0.1f);
        const float Ad = fminf(fmaxf(-eA * dt, -20.f), 0.f);
        const float dec = __expf(Ad);
        const float ks = kval * ps;
        const float phi = ks / (1.0f + fabsf(ks)) * th;
        const float kvw = kval * dt;
        float sp, cq;
        __sincosf(phi, &sp, &cq);
        are = fmaf(dec, are, kvw * cq);
        aim = fmaf(dec, aim, kvw * sp);
        P *= dec;
        acc[((size_t)bk * LL + t) * HH + h] = make_float2(are, aim);
        if (h == 0) pcum[(size_t)bk * LL + t] = P;
        zm3 = zm2; zm2 = zm1; zm1 = zm0;
        zs3 = zs2; zs2 = zs1; zs1 = zs0;
    }
    cend[(size_t)blk * HH + h] = make_float2(are, aim);
    if (h == 0) cp[blk] = P;
}

// ---------------- scan phase B ----------------
__launch_bounds__(128)
__global__ void scan_b(const float* __restrict__ cend, const float* __restrict__ cp,
                       float* __restrict__ carry) {
    const int bk = blockIdx.x;
    const int c = threadIdx.x;
    float cur = 0.f;
    for (int ch = 0; ch < NCHUNK; ++ch) {
        const size_t idx = (size_t)bk * NCHUNK + ch;
        carry[idx * 128 + c] = cur;
        cur = fmaf(cp[idx], cur, cend[idx * 128 + c]);
    }
}

// ---------------- combine (wave-per-token, barrier-free): q-conv+rms, fixup, q-match, gate, rms ----------------
// block 256 = 4 waves, each wave owns one token. All reductions via 64-lane shfl; q staged
// in per-wave LDS slab (same-wave write->read: compiler inserts lgkmcnt, no __syncthreads).
__launch_bounds__(256)
__global__ void combine_wave(const float2* __restrict__ acc, const float* __restrict__ pcum,
                             const float2* __restrict__ carry, const ushort_t* __restrict__ Zb,
                             const float* __restrict__ conv_w, const float* __restrict__ wq,
                             const float* __restrict__ wintG, const float* __restrict__ W_gate,
                             const float* __restrict__ gn_weight,
                             ushort_t* __restrict__ ocnB, ushort_t* __restrict__ cskB) {
    __shared__ float q_sh[4][DIM_Q];
    const int w = threadIdx.x >> 6, lane = threadIdx.x & 63;
    const int tok = blockIdx.x * 4 + w;
    const int b = tok / LL, t = tok % LL;
    const int chunk = t / LCHUNK;
    const size_t zrow = (size_t)tok * DIM_TOTAL;

    // cskip: lanes 0..47 copy 4 bf16 each (8B aligned both sides)
    if (lane < 48) {
        const ushort4 v = *reinterpret_cast<const ushort4*>(&Zb[zrow + DIM_CONV + lane * 4]);
        *reinterpret_cast<ushort4*>(&cskB[(size_t)tok * DIM_SKIP + lane * 4]) = v;
    }

    // gate logits (wave-uniform broadcast loads)
    float gl[KK];
    #pragma unroll
    for (int i = 0; i < KK; ++i) gl[i] = bf2f(Zb[zrow + DIM_CONV + DIM_SKIP + i]);

    // q = rms(silu(conv(q_raw)), 768) * wq — 12 channels per lane
    float u[12];
    float ssq = 0.f;
    #pragma unroll
    for (int i = 0; i < 12; ++i) {
        const int c = i * 64 + lane;
        const int ch = DIM_MEMT + c;
        float s = 0.f;
        #pragma unroll
        for (int j = 0; j < KSZ; ++j) {
            const int tt2 = t + j - (KSZ - 1);
            if (tt2 >= 0)
                s = fmaf(conv_w[j * DIM_CONV + ch],
                         bf2f(Zb[((size_t)(b * LL + tt2)) * DIM_TOTAL + ch]), s);
        }
        const float uu = s * sigm(s);
        u[i] = uu;
        ssq = fmaf(uu, uu, ssq);
    }
    ssq = waveReduceSum(ssq);
    const float qrs = rsqrtf(ssq * (1.0f / (float)DIM_Q) + 1e-6f);
    #pragma unroll
    for (int i = 0; i < 12; ++i) {
        const int c = i * 64 + lane;
        q_sh[w][c] = u[i] * qrs * wq[c];
    }

    // main loop: lane = h, iterate k. q2 reloaded once per kq pair.
    float gre[KK], gim[KK];
    float part2 = 0.f;
    float2 q2 = make_float2(0.f, 0.f);
    #pragma unroll
    for (int k = 0; k < KK; ++k) {
        if ((k & 1) == 0)
            q2 = *reinterpret_cast<const float2*>(&q_sh[w][(k >> 1) * 128 + 2 * lane]);
        const size_t bkL = (size_t)(b * KK + k) * LL + t;
        const float pc = pcum[bkL];
        const float2 a2 = acc[bkL * HH + lane];
        const float2 c2 = carry[((size_t)(b * KK + k) * NCHUNK + chunk) * HH + lane];
        const float re = fmaf(pc, c2.x, a2.x);
        const float im = fmaf(pc, c2.y, a2.y);
        const float wint = wintG[k * HH + lane];
        const float ore = (re * q2.x + im * q2.y) * wint;
        const float oim = (im * q2.x - re * q2.y) * wint;
        float gr = 0.f, gi = 0.f;
        #pragma unroll
        for (int i = 0; i < KK; ++i) {
            gr = fmaf(gl[i], W_gate[i * DGATE + k * 128 + lane], gr);
            gi = fmaf(gl[i], W_gate[i * DGATE + k * 128 + 64 + lane], gi);
        }
        gre[k] = ore * sigm(gr);
        gim[k] = oim * sigm(gi);
        part2 = fmaf(gre[k], gre[k], part2);
        part2 = fmaf(gim[k], gim[k], part2);
    }
    part2 = waveReduceSum(part2);
    const float rs = rsqrtf(part2 * (1.0f / (float)DGATE) + 1e-6f);
    #pragma unroll
    for (int k = 0; k < KK; ++k) {
        const int cre = k * 128 + lane, cim = k * 128 + 64 + lane;
        ocnB[(size_t)tok * DGATE + cre] = f2bf(gre[k] * rs * gn_weight[cre]);
        ocnB[(size_t)tok * DGATE + cim] = f2bf(gim[k] * rs * gn_weight[cim]);
    }
}

// ---------------- launch ----------------
static inline size_t pass_need_bytes(int TP) {
    const size_t BP = (size_t)TP / LL;
    size_t total = 0;
    total += (size_t)TP * DIM_TOTAL * 2;            // Zb bf16
    total += (size_t)TP * KK * HH * 8;              // acc f32x2 (aliases WinT, then Y)
    total += (size_t)TP * KK * 4;                   // pcum
    total += BP * KK * NCHUNK * HH * 8;             // cend
    total += BP * KK * NCHUNK * 4;                  // cp
    total += BP * KK * NCHUNK * HH * 8;             // carry
    total += (size_t)TP * (DGATE + DIM_SKIP) * 2;   // ocnB + cskB (aliases xb)
    total += 8ull * 1024 * 1024;                    // WoutT + Btv + Btg + wint
    return total;
}

extern "C" void kernel_launch(void* const* d_in, const int* in_sizes, int n_in,
                              void* d_out, int out_size, void* d_ws, size_t ws_size,
                              hipStream_t stream) {
    const float* x           = (const float*)d_in[0];
    const float* W_in        = (const float*)d_in[1];
    const float* conv_w      = (const float*)d_in[2];
    const float* wk          = (const float*)d_in[3];
    const float* wq          = (const float*)d_in[4];
    const float* theta_raw   = (const float*)d_in[5];
    const float* w_int_raw   = (const float*)d_in[6];
    const float* dt_scale    = (const float*)d_in[7];
    const float* dt_bias     = (const float*)d_in[8];
    const float* log_A       = (const float*)d_in[9];
    const float* phase_scale = (const float*)d_in[10];
    const float* W_gate      = (const float*)d_in[11];
    const float* gn_weight   = (const float*)d_in[12];
    const float* W_readout   = (const float*)d_in[13];
    const float* W_skip      = (const float*)d_in[14];
    const float* W_out       = (const float*)d_in[15];
    float* out = (float*)d_out;

    int passes = 4;
    if (ws_size >= pass_need_bytes(TTOK))        passes = 1;
    else if (ws_size >= pass_need_bytes(TTOK/2)) passes = 2;

    const int BP = BB / passes;
    const int TP = BP * LL;

    char* p = (char*)d_ws;
    ushort_t* Zb   = (ushort_t*)p;               p += (size_t)TP * DIM_TOTAL * 2;
    char* accR     = p;
    float2* acc    = (float2*)p;                 p += (size_t)TP * KK * HH * 8;
    float* pcum    = (float*)p;                  p += (size_t)TP * KK * 4;
    float2* cendv  = (float2*)p;                 p += (size_t)BP * KK * NCHUNK * HH * 8;
    float* cp      = (float*)p;                  p += (size_t)BP * KK * NCHUNK * 4;
    float2* carry  = (float2*)p;                 p += (size_t)BP * KK * NCHUNK * HH * 8;
    char* ocnR     = p;
    ushort_t* ocnB = (ushort_t*)p;               p += (size_t)TP * DGATE * 2;
    ushort_t* cskB = (ushort_t*)p;               p += (size_t)TP * DIM_SKIP * 2;
    ushort_t* WoutT= (ushort_t*)p;               p += (size_t)768 * 2304 * 2;
    ushort_t* Btv  = (ushort_t*)p;               p += (size_t)KK * 192 * 320 * 2;
    ushort_t* Btg  = (ushort_t*)p;               p += (size_t)KK * 192 * 320 * 2;
    float* wintG   = (float*)p;                  p += (size_t)KK * HH * 4;
    // aliases (stream-serial lifetime reuse):
    ushort_t* xb   = (ushort_t*)ocnR;   // [TP][768] bf16, dead after GEMM1
    ushort_t* WinT = (ushort_t*)accR;   // [1792][768] bf16, dead after GEMM1
    ushort_t* Y    = (ushort_t*)accR;   // [TP][2304] bf16 (<= acc bytes), written after combine

    for (int pass = 0; pass < passes; ++pass) {
        const float* xp = x   + (size_t)pass * TP * DD;
        float*       op = out + (size_t)pass * TP * DD;

        // input-only preps (front-loaded)
        cast_bf16<<<1024, 256, 0, stream>>>(xp, xb, TP * DD / 4);
        transpose_cast<<<dim3(N1PAD / 32, DD / 32), dim3(32, 8), 0, stream>>>(
            W_in, WinT, DD, N1REAL, N1PAD);
        transpose_cast<<<dim3(DD / 32, (KK * 3 * HH) / 32), dim3(32, 8), 0, stream>>>(
            W_out, WoutT, KK * 3 * HH, DD, DD);
        prep_bt<<<dim3(KK, 192), 320, 0, stream>>>(W_readout, W_skip, Btv, Btg);
        prep_wint<<<3, 256, 0, stream>>>(w_int_raw, wintG);

        // 1. Zb = x @ W_in  (bf16 MFMA, bf16 output)
        mfma_gemm<true><<<dim3(TP / 128, N1PAD / 128), 256, 0, stream>>>(xb, WinT, Zb, N1REAL, DD);

        // 2. fused conv+feat+scan (mem path)
        feat_scan<<<BP * KK * NCHUNK, 64, 0, stream>>>(Zb, conv_w, wk, theta_raw, dt_scale,
                                                       dt_bias, log_A, phase_scale,
                                                       acc, pcum, cendv, cp);

        // 3. carry propagation
        scan_b<<<BP * KK, 128, 0, stream>>>((const float*)cendv, cp, (float*)carry);

        // 4. combine (wave-per-token) -> ocn bf16 + cskip bf16
        combine_wave<<<TP / 4, 256, 0, stream>>>(acc, pcum, carry, Zb, conv_w, wq, wintG,
                                                 W_gate, gn_weight, ocnB, cskB);

        // 5. Y(bf16) = val*silu(gate) of grouped MFMA GEMM (readout + skip, K=320)
        gemm2_mfma<<<dim3(TP / 128, 3, KK), 256, 0, stream>>>(ocnB, cskB, Btv, Btg, Y);

        // 6. out = Y @ W_out  (bf16 MFMA, f32 output)
        mfma_gemm<false><<<dim3(TP / 128, DD / 128), 256, 0, stream>>>(Y, WoutT, op, DD, KK * 3 * HH);
    }
}

// Round 13
// 405.276 us; speedup vs baseline: 1.0907x; 1.0907x over previous
//
#include <hip/hip_runtime.h>
#include <hip/hip_bf16.h>
#include <cstdint>
#include <cstddef>

// ---------------- problem constants ----------------
#define BB 4
#define LL 4096
#define DD 768
#define KK 12
#define HH 64
#define KSZ 4
#define DIM_MEM 768
#define DIM_MEMT 780
#define DIM_Q 768
#define DIM_CONV 1548
#define DIM_SKIP 192
#define DIM_SWH 384
#define DIM_TOTAL 1752
#define TTOK (BB*LL)
#define NCHUNK 128
#define LCHUNK 32            // LL / NCHUNK
#define N1REAL 1752
#define N1PAD 1792
#define DGATE (KK*2*HH)      // 1536

typedef unsigned short ushort_t;
typedef __attribute__((ext_vector_type(8))) short short8v;   // 8 x bf16 (4 VGPRs)
typedef __attribute__((ext_vector_type(4))) float f32x4;

// ---------------- helpers ----------------
__device__ __forceinline__ float sigm(float x) {
    return __builtin_amdgcn_rcpf(1.0f + __expf(-x));
}
__device__ __forceinline__ float softplus_fast(float x) {
    return (x > 0.f) ? (x + __logf(1.0f + __expf(-x))) : __logf(1.0f + __expf(x));
}
__device__ __forceinline__ ushort_t f2bf(float f) {
    __hip_bfloat16 h = __float2bfloat16(f);
    return __builtin_bit_cast(ushort_t, h);
}
__device__ __forceinline__ float bf2f(ushort_t u) {
    const uint32_t i = ((uint32_t)u) << 16;
    return __builtin_bit_cast(float, i);
}
__device__ __forceinline__ float blockReduceSum256(float v, float* sbuf) {
    #pragma unroll
    for (int off = 32; off > 0; off >>= 1) v += __shfl_xor(v, off);
    const int wid = threadIdx.x >> 6;
    __syncthreads();
    if ((threadIdx.x & 63) == 0) sbuf[wid] = v;
    __syncthreads();
    return sbuf[0] + sbuf[1] + sbuf[2] + sbuf[3];
}
__device__ __forceinline__ void gload_lds16(const void* g, void* l) {
    __builtin_amdgcn_global_load_lds(
        (const __attribute__((address_space(1))) void*)g,
        (__attribute__((address_space(3))) void*)l, 16, 0, 0);
}

// ---------------- cast fp32 -> bf16 (vectorized) ----------------
__launch_bounds__(256)
__global__ void cast_bf16(const float* __restrict__ in, ushort_t* __restrict__ out, int n4) {
    const int stride = gridDim.x * 256;
    for (int i = blockIdx.x * 256 + threadIdx.x; i < n4; i += stride) {
        const float4 v = reinterpret_cast<const float4*>(in)[i];
        ushort4 o;
        o.x = f2bf(v.x); o.y = f2bf(v.y); o.z = f2bf(v.z); o.w = f2bf(v.w);
        reinterpret_cast<ushort4*>(out)[i] = o;
    }
}

// ---------------- transpose + cast: in[R][Cc] f32 -> out[Cpad][R] bf16 (zero pad) ----------------
__global__ void transpose_cast(const float* __restrict__ in, ushort_t* __restrict__ out,
                               int R, int Cc, int Cpad) {
    __shared__ float tile[32][33];
    const int tx = threadIdx.x, ty = threadIdx.y;
    const int c0 = blockIdx.x * 32, r0 = blockIdx.y * 32;
    #pragma unroll
    for (int rr = ty; rr < 32; rr += 8) {
        const int r = r0 + rr, c = c0 + tx;
        tile[rr][tx] = (r < R && c < Cc) ? in[(size_t)r * Cc + c] : 0.f;
    }
    __syncthreads();
    #pragma unroll
    for (int rr = ty; rr < 32; rr += 8) {
        const int c = c0 + rr, r = r0 + tx;
        if (c < Cpad && r < R)
            out[(size_t)c * R + r] = f2bf(tile[tx][rr]);
    }
}

// ---------------- build Bt for gemm2: Btv/Btg [12][192][320] bf16 ----------------
__global__ void prep_bt(const float* __restrict__ Wr, const float* __restrict__ Wskip,
                        ushort_t* __restrict__ Btv, ushort_t* __restrict__ Btg) {
    const int k = blockIdx.x, n = blockIdx.y, kk = threadIdx.x;   // block 320
    float v, g;
    if (kk < 128) {
        const size_t base = ((size_t)k * 128 + kk) * DIM_SWH;
        v = Wr[base + n];
        g = Wr[base + 192 + n];
    } else {
        const size_t base = (size_t)(kk - 128) * (KK * DIM_SWH) + (size_t)k * DIM_SWH;
        v = Wskip[base + n];
        g = Wskip[base + 192 + n];
    }
    const size_t o = ((size_t)k * 192 + n) * 320 + kk;
    Btv[o] = f2bf(v);
    Btg[o] = f2bf(g);
}

// ---------------- prep wint: wint[768] = exp(clamp(w_int_raw, -5, 5))  (accurate, runs once) ----------------
__global__ void prep_wint(const float* __restrict__ w_int_raw, float* __restrict__ wint) {
    const int i = blockIdx.x * 256 + threadIdx.x;
    if (i < KK * HH) {
        float wr = w_int_raw[i];
        wr = fminf(fmaxf(wr, -5.f), 5.f);
        wint[i] = expf(wr);
    }
}

// ---------------- bf16 MFMA GEMM (BK=32, 5 blocks/CU): C[M,Nreal] = A @ Bt^T ----------------
template <bool BF16OUT>
__launch_bounds__(256)
__global__ void mfma_gemm(const ushort_t* __restrict__ A, const ushort_t* __restrict__ Bt,
                          void* __restrict__ Cv, int Nreal, int K) {
    __shared__ ushort_t As[2][128 * 32];
    __shared__ ushort_t Bs[2][128 * 32];
    const int tid = threadIdx.x;
    const int lane = tid & 63, w = tid >> 6;
    const int m0 = blockIdx.x * 128, n0 = blockIdx.y * 128;
    const int wm = w & 1, wn = w >> 1;
    const int nkt = K >> 5;
    const int lrow = lane >> 2;          // 0..15
    const int lcol = (lane & 3) * 8;     // 0,8,16,24

    f32x4 acc[4][4] = {};

    auto stage = [&](int buf, int k0) {
        #pragma unroll
        for (int i = 0; i < 2; ++i) {
            const int seg = w * 2 + i;               // 0..7 (16 rows each)
            const int row = seg * 16 + lrow;
            gload_lds16(&A[(size_t)(m0 + row) * K + k0 + lcol], &As[buf][seg * 512]);
            gload_lds16(&Bt[(size_t)(n0 + row) * K + k0 + lcol], &Bs[buf][seg * 512]);
        }
    };

    stage(0, 0);
    for (int kt = 0; kt < nkt; ++kt) {
        const int cur = kt & 1;
        __syncthreads();
        if (kt + 1 < nkt) stage(cur ^ 1, (kt + 1) << 5);
        short8v a[4], b[4];
        #pragma unroll
        for (int i = 0; i < 4; ++i)
            a[i] = *(const short8v*)&As[cur][(wm * 64 + i * 16 + (lane & 15)) * 32 + (lane >> 4) * 8];
        #pragma unroll
        for (int j = 0; j < 4; ++j)
            b[j] = *(const short8v*)&Bs[cur][(wn * 64 + j * 16 + (lane & 15)) * 32 + (lane >> 4) * 8];
        #pragma unroll
        for (int i = 0; i < 4; ++i)
            #pragma unroll
            for (int j = 0; j < 4; ++j)
                acc[i][j] = __builtin_amdgcn_mfma_f32_16x16x32_bf16(a[i], b[j], acc[i][j], 0, 0, 0);
    }
    #pragma unroll
    for (int i = 0; i < 4; ++i) {
        const int rbase = m0 + wm * 64 + i * 16 + (lane >> 4) * 4;
        #pragma unroll
        for (int j = 0; j < 4; ++j) {
            const int col = n0 + wn * 64 + j * 16 + (lane & 15);
            if (col < Nreal) {
                #pragma unroll
                for (int r = 0; r < 4; ++r) {
                    if constexpr (BF16OUT)
                        ((ushort_t*)Cv)[(size_t)(rbase + r) * Nreal + col] = f2bf(acc[i][j][r]);
                    else
                        ((float*)Cv)[(size_t)(rbase + r) * Nreal + col] = acc[i][j][r];
                }
            }
        }
    }
}

// ---------------- gemm2 MFMA: per-k grouped GEMM with fused val*silu(gate) ----------------
__launch_bounds__(256)
__global__ void gemm2_mfma(const ushort_t* __restrict__ OCNb, const ushort_t* __restrict__ CskB,
                           const ushort_t* __restrict__ Btv, const ushort_t* __restrict__ Btg,
                           ushort_t* __restrict__ Y) {
    __shared__ ushort_t As[2][128 * 64];
    __shared__ ushort_t Bvs[2][64 * 64];
    __shared__ ushort_t Bgs[2][64 * 64];
    const int tid = threadIdx.x;
    const int lane = tid & 63, w = tid >> 6;
    const int m0 = blockIdx.x * 128;
    const int n0 = blockIdx.y * 64;
    const int k  = blockIdx.z;
    const int wm = w & 1, wn = w >> 1;
    const int lrow = lane >> 3;
    const int lcol = (lane & 7) * 8;
    const ushort_t* btv = Btv + (size_t)k * 192 * 320;
    const ushort_t* btg = Btg + (size_t)k * 192 * 320;

    f32x4 accV[4][2] = {};
    f32x4 accG[4][2] = {};

    auto stage = [&](int buf, int kt) {
        #pragma unroll
        for (int i = 0; i < 4; ++i) {
            const int seg = w * 4 + i;
            const int row = seg * 8 + lrow;
            const ushort_t* src = (kt < 2)
                ? OCNb + (size_t)(m0 + row) * DGATE + k * 128 + kt * 64 + lcol
                : CskB + (size_t)(m0 + row) * DIM_SKIP + (kt - 2) * 64 + lcol;
            gload_lds16(src, &As[buf][seg * 512]);
        }
        #pragma unroll
        for (int i = 0; i < 2; ++i) {
            const int seg = w * 2 + i;
            const int row = seg * 8 + lrow;
            gload_lds16(btv + (size_t)(n0 + row) * 320 + kt * 64 + lcol, &Bvs[buf][seg * 512]);
            gload_lds16(btg + (size_t)(n0 + row) * 320 + kt * 64 + lcol, &Bgs[buf][seg * 512]);
        }
    };

    stage(0, 0);
    for (int kt = 0; kt < 5; ++kt) {
        const int cur = kt & 1;
        __syncthreads();
        if (kt + 1 < 5) stage(cur ^ 1, kt + 1);
        #pragma unroll
        for (int kk = 0; kk < 2; ++kk) {
            short8v a[4], bv[2], bg[2];
            #pragma unroll
            for (int i = 0; i < 4; ++i)
                a[i] = *(const short8v*)&As[cur][(wm * 64 + i * 16 + (lane & 15)) * 64 + kk * 32 + (lane >> 4) * 8];
            #pragma unroll
            for (int j = 0; j < 2; ++j) {
                bv[j] = *(const short8v*)&Bvs[cur][(wn * 32 + j * 16 + (lane & 15)) * 64 + kk * 32 + (lane >> 4) * 8];
                bg[j] = *(const short8v*)&Bgs[cur][(wn * 32 + j * 16 + (lane & 15)) * 64 + kk * 32 + (lane >> 4) * 8];
            }
            #pragma unroll
            for (int i = 0; i < 4; ++i)
                #pragma unroll
                for (int j = 0; j < 2; ++j) {
                    accV[i][j] = __builtin_amdgcn_mfma_f32_16x16x32_bf16(a[i], bv[j], accV[i][j], 0, 0, 0);
                    accG[i][j] = __builtin_amdgcn_mfma_f32_16x16x32_bf16(a[i], bg[j], accG[i][j], 0, 0, 0);
                }
        }
    }
    #pragma unroll
    for (int i = 0; i < 4; ++i) {
        const int rbase = m0 + wm * 64 + i * 16 + (lane >> 4) * 4;
        #pragma unroll
        for (int j = 0; j < 2; ++j) {
            const int col = k * 192 + n0 + wn * 32 + j * 16 + (lane & 15);
            #pragma unroll
            for (int r = 0; r < 4; ++r) {
                const float g = accG[i][j][r];
                Y[(size_t)(rbase + r) * (KK * 3 * HH) + col] = f2bf(accV[i][j][r] * (g * sigm(g)));
            }
        }
    }
}

// ---------------- fused feature + scan: per (b,k,chunk32), 64 lanes = 64 heads ----------------
// acc layout TOKEN-MAJOR: acc[(b*LL+t)*KK + k][h] (float2); pcum[(b*LL+t)*KK + k].
__launch_bounds__(64)
__global__ void feat_scan(const ushort_t* __restrict__ Zb, const float* __restrict__ conv_w,
                          const float* __restrict__ wk, const float* __restrict__ theta_raw,
                          const float* __restrict__ dt_scale, const float* __restrict__ dt_bias,
                          const float* __restrict__ log_A, const float* __restrict__ phase_scale,
                          float2* __restrict__ acc, float* __restrict__ pcum,
                          float2* __restrict__ cend, float* __restrict__ cp) {
    const int blk = blockIdx.x;                  // (b*KK+k)*NCHUNK + chunk
    const int bk = blk / NCHUNK, chunk = blk - bk * NCHUNK;
    const int b = bk / KK, k = bk - b * KK;
    const int h = threadIdx.x;
    const int t0 = chunk * LCHUNK;
    const int cm_ch = k * HH + h;
    const int cs_ch = DIM_MEM + k;

    const float w0 = conv_w[0 * DIM_CONV + cm_ch];
    const float w1 = conv_w[1 * DIM_CONV + cm_ch];
    const float w2 = conv_w[2 * DIM_CONV + cm_ch];
    const float w3 = conv_w[3 * DIM_CONV + cm_ch];
    const float s0 = conv_w[0 * DIM_CONV + cs_ch];
    const float s1 = conv_w[1 * DIM_CONV + cs_ch];
    const float s2 = conv_w[2 * DIM_CONV + cs_ch];
    const float s3 = conv_w[3 * DIM_CONV + cs_ch];
    const float wkh = wk[h];
    const float th = 0.001f + (3.0f - 0.001f) * sigm(theta_raw[cm_ch]);
    const float ps = phase_scale[k];
    const float dts = dt_scale[k], dtb = dt_bias[k];
    const float eA = expf(log_A[k]);

    const size_t rowb = (size_t)b * LL;
    auto zm_at = [&](int t) -> float {
        return (t >= 0) ? bf2f(Zb[(rowb + t) * DIM_TOTAL + cm_ch]) : 0.f;
    };
    auto zs_at = [&](int t) -> float {
        return (t >= 0) ? bf2f(Zb[(rowb + t) * DIM_TOTAL + cs_ch]) : 0.f;
    };
    float zm3 = zm_at(t0 - 3), zm2 = zm_at(t0 - 2), zm1 = zm_at(t0 - 1);
    float zs3 = zs_at(t0 - 3), zs2 = zs_at(t0 - 2), zs1 = zs_at(t0 - 1);

    float are = 0.f, aim = 0.f, P = 1.f;
    #pragma unroll 4
    for (int tt = 0; tt < LCHUNK; ++tt) {
        const int t = t0 + tt;
        const float zm0 = bf2f(Zb[(rowb + t) * DIM_TOTAL + cm_ch]);
        const float zs0 = bf2f(Zb[(rowb + t) * DIM_TOTAL + cs_ch]);
        float cm = fmaf(w0, zm3, fmaf(w1, zm2, fmaf(w2, zm1, w3 * zm0)));
        float cs = fmaf(s0, zs3, fmaf(s1, zs2, fmaf(s2, zs1, s3 * zs0)));
        const float um = cm * sigm(cm);
        const float us = cs * sigm(cs);
        float ssq = um * um;
        #pragma unroll
        for (int off = 32; off > 0; off >>= 1) ssq += __shfl_xor(ssq, off);
        const float kval = um * rsqrtf(ssq * (1.0f / (float)HH) + 1e-6f) * wkh;
        float lin = fminf(fmaxf(fmaf(dts, us, dtb), -20.f), 20.f);
        float dt = fminf(fmaxf(softplus_fast(lin), 0.001f), 0.1f);
        const float Ad = fminf(fmaxf(-eA * dt, -20.f), 0.f);
        const float dec = __expf(Ad);
        const float ks = kval * ps;
        const float phi = ks / (1.0f + fabsf(ks)) * th;
        const float kvw = kval * dt;
        float sp, cq;
        __sincosf(phi, &sp, &cq);
        are = fmaf(dec, are, kvw * cq);
        aim = fmaf(dec, aim, kvw * sp);
        P *= dec;
        const size_t tokK = (rowb + t) * KK + k;
        acc[tokK * HH + h] = make_float2(are, aim);
        if (h == 0) pcum[tokK] = P;
        zm3 = zm2; zm2 = zm1; zm1 = zm0;
        zs3 = zs2; zs2 = zs1; zs1 = zs0;
    }
    cend[(size_t)blk * HH + h] = make_float2(are, aim);
    if (h == 0) cp[blk] = P;
}

// ---------------- scan phase B ----------------
__launch_bounds__(128)
__global__ void scan_b(const float* __restrict__ cend, const float* __restrict__ cp,
                       float* __restrict__ carry) {
    const int bk = blockIdx.x;
    const int c = threadIdx.x;
    float cur = 0.f;
    for (int ch = 0; ch < NCHUNK; ++ch) {
        const size_t idx = (size_t)bk * NCHUNK + ch;
        carry[idx * 128 + c] = cur;
        cur = fmaf(cp[idx], cur, cend[idx * 128 + c]);
    }
}

// ---------------- combine (R11 form, token-major acc): q-conv+rms, fixup, q-match, gate, rms ----------------
__launch_bounds__(256)
__global__ void combine_kernel(const float2* __restrict__ acc, const float* __restrict__ pcum,
                               const float2* __restrict__ carry, const ushort_t* __restrict__ Zb,
                               const float* __restrict__ conv_w, const float* __restrict__ wq,
                               const float* __restrict__ wintG, const float* __restrict__ W_gate,
                               const float* __restrict__ gn_weight,
                               ushort_t* __restrict__ ocnB, ushort_t* __restrict__ cskB) {
    __shared__ float q_sh[DIM_Q];
    __shared__ float g_sh[DGATE];
    __shared__ float gl[KK];
    __shared__ float red[8];
    const int tok = blockIdx.x;
    const int b = tok / LL, t = tok % LL;
    const int tid = threadIdx.x;
    const int chunk = t / LCHUNK;
    const size_t zrow = (size_t)tok * DIM_TOTAL;
    const size_t tokK = (size_t)tok * KK;

    if (tid < KK) gl[tid] = bf2f(Zb[zrow + DIM_CONV + DIM_SKIP + tid]);
    if (tid < DIM_SKIP) cskB[(size_t)tok * DIM_SKIP + tid] = Zb[zrow + DIM_CONV + tid];

    // q = rms(silu(conv(q_raw)), 768) * wq
    float part = 0.f;
    float qv[3];
    #pragma unroll
    for (int it = 0; it < 3; ++it) {
        const int c = tid + it * 256;
        const int ch = DIM_MEMT + c;
        float s = 0.f;
        #pragma unroll
        for (int j = 0; j < KSZ; ++j) {
            const int tt2 = t + j - (KSZ - 1);
            if (tt2 >= 0)
                s = fmaf(conv_w[j * DIM_CONV + ch],
                         bf2f(Zb[((size_t)(b * LL + tt2)) * DIM_TOTAL + ch]), s);
        }
        const float u = s * sigm(s);
        qv[it] = u;
        part = fmaf(u, u, part);
    }
    const float qss = blockReduceSum256(part, red);
    const float qrs = rsqrtf(qss / (float)DIM_Q + 1e-6f);
    #pragma unroll
    for (int it = 0; it < 3; ++it) {
        const int c = tid + it * 256;
        q_sh[c] = qv[it] * qrs * wq[c];
    }
    __syncthreads();

    float part2 = 0.f;
    #pragma unroll
    for (int it = 0; it < 3; ++it) {
        const int p = tid + it * 256;        // p = k*64 + h -> acc[tokK*64*12 + p] contiguous
        const int k = p >> 6, h = p & 63;
        const int kq = k >> 1;
        const float pc = pcum[tokK + k];
        const float2 a2 = acc[tokK * HH + p];
        const float2 c2 = carry[((size_t)(b * KK + k) * NCHUNK + chunk) * HH + h];
        const float re = fmaf(pc, c2.x, a2.x);
        const float im = fmaf(pc, c2.y, a2.y);
        const float qre = q_sh[kq * 128 + 2 * h];
        const float qim = q_sh[kq * 128 + 2 * h + 1];
        const float wint = wintG[p];
        const float ore = (re * qre + im * qim) * wint;
        const float oim = (im * qre - re * qim) * wint;
        float gr = 0.f, gi = 0.f;
        const int cre = k * 128 + h, cim = k * 128 + 64 + h;
        #pragma unroll
        for (int i = 0; i < KK; ++i) {
            gr = fmaf(gl[i], W_gate[i * DGATE + cre], gr);
            gi = fmaf(gl[i], W_gate[i * DGATE + cim], gi);
        }
        const float g_re = ore * sigm(gr);
        const float g_im = oim * sigm(gi);
        g_sh[cre] = g_re;
        g_sh[cim] = g_im;
        part2 = fmaf(g_re, g_re, part2);
        part2 = fmaf(g_im, g_im, part2);
    }
    const float ss = blockReduceSum256(part2, red);
    const float rs = rsqrtf(ss / (float)DGATE + 1e-6f);
    __syncthreads();
    #pragma unroll
    for (int it = 0; it < 6; ++it) {
        const int c = tid + it * 256;
        ocnB[(size_t)tok * DGATE + c] = f2bf(g_sh[c] * rs * gn_weight[c]);
    }
}

// ---------------- launch ----------------
static inline size_t pass_need_bytes(int TP) {
    const size_t BP = (size_t)TP / LL;
    size_t total = 0;
    total += (size_t)TP * DIM_TOTAL * 2;            // Zb bf16
    total += (size_t)TP * KK * HH * 8;              // acc f32x2 (aliases WinT, then Y)
    total += (size_t)TP * KK * 4;                   // pcum
    total += BP * KK * NCHUNK * HH * 8;             // cend
    total += BP * KK * NCHUNK * 4;                  // cp
    total += BP * KK * NCHUNK * HH * 8;             // carry
    total += (size_t)TP * (DGATE + DIM_SKIP) * 2;   // ocnB + cskB (aliases xb)
    total += 8ull * 1024 * 1024;                    // WoutT + Btv + Btg + wint
    return total;
}

extern "C" void kernel_launch(void* const* d_in, const int* in_sizes, int n_in,
                              void* d_out, int out_size, void* d_ws, size_t ws_size,
                              hipStream_t stream) {
    const float* x           = (const float*)d_in[0];
    const float* W_in        = (const float*)d_in[1];
    const float* conv_w      = (const float*)d_in[2];
    const float* wk          = (const float*)d_in[3];
    const float* wq          = (const float*)d_in[4];
    const float* theta_raw   = (const float*)d_in[5];
    const float* w_int_raw   = (const float*)d_in[6];
    const float* dt_scale    = (const float*)d_in[7];
    const float* dt_bias     = (const float*)d_in[8];
    const float* log_A       = (const float*)d_in[9];
    const float* phase_scale = (const float*)d_in[10];
    const float* W_gate      = (const float*)d_in[11];
    const float* gn_weight   = (const float*)d_in[12];
    const float* W_readout   = (const float*)d_in[13];
    const float* W_skip      = (const float*)d_in[14];
    const float* W_out       = (const float*)d_in[15];
    float* out = (float*)d_out;

    int passes = 4;
    if (ws_size >= pass_need_bytes(TTOK))        passes = 1;
    else if (ws_size >= pass_need_bytes(TTOK/2)) passes = 2;

    const int BP = BB / passes;
    const int TP = BP * LL;

    char* p = (char*)d_ws;
    ushort_t* Zb   = (ushort_t*)p;               p += (size_t)TP * DIM_TOTAL * 2;
    char* accR     = p;
    float2* acc    = (float2*)p;                 p += (size_t)TP * KK * HH * 8;
    float* pcum    = (float*)p;                  p += (size_t)TP * KK * 4;
    float2* cendv  = (float2*)p;                 p += (size_t)BP * KK * NCHUNK * HH * 8;
    float* cp      = (float*)p;                  p += (size_t)BP * KK * NCHUNK * 4;
    float2* carry  = (float2*)p;                 p += (size_t)BP * KK * NCHUNK * HH * 8;
    char* ocnR     = p;
    ushort_t* ocnB = (ushort_t*)p;               p += (size_t)TP * DGATE * 2;
    ushort_t* cskB = (ushort_t*)p;               p += (size_t)TP * DIM_SKIP * 2;
    ushort_t* WoutT= (ushort_t*)p;               p += (size_t)768 * 2304 * 2;
    ushort_t* Btv  = (ushort_t*)p;               p += (size_t)KK * 192 * 320 * 2;
    ushort_t* Btg  = (ushort_t*)p;               p += (size_t)KK * 192 * 320 * 2;
    float* wintG   = (float*)p;                  p += (size_t)KK * HH * 4;
    // aliases (stream-serial lifetime reuse):
    ushort_t* xb   = (ushort_t*)ocnR;   // [TP][768] bf16, dead after GEMM1
    ushort_t* WinT = (ushort_t*)accR;   // [1792][768] bf16, dead after GEMM1
    ushort_t* Y    = (ushort_t*)accR;   // [TP][2304] bf16 (<= acc bytes), written after combine

    for (int pass = 0; pass < passes; ++pass) {
        const float* xp = x   + (size_t)pass * TP * DD;
        float*       op = out + (size_t)pass * TP * DD;

        // input-only preps (front-loaded)
        cast_bf16<<<1024, 256, 0, stream>>>(xp, xb, TP * DD / 4);
        transpose_cast<<<dim3(N1PAD / 32, DD / 32), dim3(32, 8), 0, stream>>>(
            W_in, WinT, DD, N1REAL, N1PAD);
        transpose_cast<<<dim3(DD / 32, (KK * 3 * HH) / 32), dim3(32, 8), 0, stream>>>(
            W_out, WoutT, KK * 3 * HH, DD, DD);
        prep_bt<<<dim3(KK, 192), 320, 0, stream>>>(W_readout, W_skip, Btv, Btg);
        prep_wint<<<3, 256, 0, stream>>>(w_int_raw, wintG);

        // 1. Zb = x @ W_in  (bf16 MFMA, bf16 output)
        mfma_gemm<true><<<dim3(TP / 128, N1PAD / 128), 256, 0, stream>>>(xb, WinT, Zb, N1REAL, DD);

        // 2. fused conv+feat+scan (token-major acc/pcum)
        feat_scan<<<BP * KK * NCHUNK, 64, 0, stream>>>(Zb, conv_w, wk, theta_raw, dt_scale,
                                                       dt_bias, log_A, phase_scale,
                                                       acc, pcum, cendv, cp);

        // 3. carry propagation
        scan_b<<<BP * KK, 128, 0, stream>>>((const float*)cendv, cp, (float*)carry);

        // 4. combine -> ocn bf16 + cskip bf16
        combine_kernel<<<TP, 256, 0, stream>>>(acc, pcum, carry, Zb, conv_w, wq, wintG,
                                               W_gate, gn_weight, ocnB, cskB);

        // 5. Y(bf16) = val*silu(gate) of grouped MFMA GEMM (readout + skip, K=320)
        gemm2_mfma<<<dim3(TP / 128, 3, KK), 256, 0, stream>>>(ocnB, cskB, Btv, Btg, Y);

        // 6. out = Y @ W_out  (bf16 MFMA, f32 output)
        mfma_gemm<false><<<dim3(TP / 128, DD / 128), 256, 0, stream>>>(Y, WoutT, op, DD, KK * 3 * HH);
    }
}

// Round 14
// 394.744 us; speedup vs baseline: 1.1198x; 1.0267x over previous
//
#include <hip/hip_runtime.h>
#include <hip/hip_bf16.h>
#include <cstdint>
#include <cstddef>

// ---------------- problem constants ----------------
#define BB 4
#define LL 4096
#define DD 768
#define KK 12
#define HH 64
#define KSZ 4
#define DIM_MEM 768
#define DIM_MEMT 780
#define DIM_Q 768
#define DIM_CONV 1548
#define DIM_SKIP 192
#define DIM_SWH 384
#define DIM_TOTAL 1752
#define TTOK (BB*LL)
#define NCHUNK 128
#define LCHUNK 32            // LL / NCHUNK
#define N1REAL 1752
#define N1PAD 1792
#define DGATE (KK*2*HH)      // 1536

typedef unsigned short ushort_t;
typedef __attribute__((ext_vector_type(8))) short short8v;   // 8 x bf16 (4 VGPRs)
typedef __attribute__((ext_vector_type(4))) float f32x4;

// ---------------- helpers ----------------
__device__ __forceinline__ float sigm(float x) {
    return __builtin_amdgcn_rcpf(1.0f + __expf(-x));
}
__device__ __forceinline__ float softplus_fast(float x) {
    return (x > 0.f) ? (x + __logf(1.0f + __expf(-x))) : __logf(1.0f + __expf(x));
}
__device__ __forceinline__ ushort_t f2bf(float f) {
    __hip_bfloat16 h = __float2bfloat16(f);
    return __builtin_bit_cast(ushort_t, h);
}
__device__ __forceinline__ float bf2f(ushort_t u) {
    const uint32_t i = ((uint32_t)u) << 16;
    return __builtin_bit_cast(float, i);
}
__device__ __forceinline__ float blockReduceSum256(float v, float* sbuf) {
    #pragma unroll
    for (int off = 32; off > 0; off >>= 1) v += __shfl_xor(v, off);
    const int wid = threadIdx.x >> 6;
    __syncthreads();
    if ((threadIdx.x & 63) == 0) sbuf[wid] = v;
    __syncthreads();
    return sbuf[0] + sbuf[1] + sbuf[2] + sbuf[3];
}
__device__ __forceinline__ void gload_lds16(const void* g, void* l) {
    __builtin_amdgcn_global_load_lds(
        (const __attribute__((address_space(1))) void*)g,
        (__attribute__((address_space(3))) void*)l, 16, 0, 0);
}

// ---------------- cast fp32 -> bf16 (vectorized) ----------------
__launch_bounds__(256)
__global__ void cast_bf16(const float* __restrict__ in, ushort_t* __restrict__ out, int n4) {
    const int stride = gridDim.x * 256;
    for (int i = blockIdx.x * 256 + threadIdx.x; i < n4; i += stride) {
        const float4 v = reinterpret_cast<const float4*>(in)[i];
        ushort4 o;
        o.x = f2bf(v.x); o.y = f2bf(v.y); o.z = f2bf(v.z); o.w = f2bf(v.w);
        reinterpret_cast<ushort4*>(out)[i] = o;
    }
}

// ---------------- transpose + cast: in[R][Cc] f32 -> out[Cpad][R] bf16 (zero pad) ----------------
__global__ void transpose_cast(const float* __restrict__ in, ushort_t* __restrict__ out,
                               int R, int Cc, int Cpad) {
    __shared__ float tile[32][33];
    const int tx = threadIdx.x, ty = threadIdx.y;
    const int c0 = blockIdx.x * 32, r0 = blockIdx.y * 32;
    #pragma unroll
    for (int rr = ty; rr < 32; rr += 8) {
        const int r = r0 + rr, c = c0 + tx;
        tile[rr][tx] = (r < R && c < Cc) ? in[(size_t)r * Cc + c] : 0.f;
    }
    __syncthreads();
    #pragma unroll
    for (int rr = ty; rr < 32; rr += 8) {
        const int c = c0 + rr, r = r0 + tx;
        if (c < Cpad && r < R)
            out[(size_t)c * R + r] = f2bf(tile[tx][rr]);
    }
}

// ---------------- build Bt for gemm2: Btv/Btg [12][192][320] bf16 ----------------
__global__ void prep_bt(const float* __restrict__ Wr, const float* __restrict__ Wskip,
                        ushort_t* __restrict__ Btv, ushort_t* __restrict__ Btg) {
    const int k = blockIdx.x, n = blockIdx.y, kk = threadIdx.x;   // block 320
    float v, g;
    if (kk < 128) {
        const size_t base = ((size_t)k * 128 + kk) * DIM_SWH;
        v = Wr[base + n];
        g = Wr[base + 192 + n];
    } else {
        const size_t base = (size_t)(kk - 128) * (KK * DIM_SWH) + (size_t)k * DIM_SWH;
        v = Wskip[base + n];
        g = Wskip[base + 192 + n];
    }
    const size_t o = ((size_t)k * 192 + n) * 320 + kk;
    Btv[o] = f2bf(v);
    Btg[o] = f2bf(g);
}

// ---------------- prep wint: wint[768] = exp(clamp(w_int_raw, -5, 5))  (accurate, runs once) ----------------
__global__ void prep_wint(const float* __restrict__ w_int_raw, float* __restrict__ wint) {
    const int i = blockIdx.x * 256 + threadIdx.x;
    if (i < KK * HH) {
        float wr = w_int_raw[i];
        wr = fminf(fmaxf(wr, -5.f), 5.f);
        wint[i] = expf(wr);
    }
}

// ---------------- gate GEMM: sigG[T,1536] = sigmoid(gate_logits[T,12] @ W_gate[12,1536]) ----------------
// 16 tokens/block, 1024 blocks (4/CU). W columns in 72 registers; logits via LDS broadcast;
// 6 independent FMA chains. sigG ALIASES ocnB (combine reads before its writes).
__launch_bounds__(256)
__global__ void gate_gemm16(const ushort_t* __restrict__ Zb, const float* __restrict__ W_gate,
                            ushort_t* sigG) {
    __shared__ float gl_sh[16][KK];
    const int tid = threadIdx.x;
    const int tok0 = blockIdx.x * 16;
    float wreg[6][KK];
    #pragma unroll
    for (int cb = 0; cb < 6; ++cb)
        #pragma unroll
        for (int i = 0; i < KK; ++i)
            wreg[cb][i] = W_gate[i * DGATE + cb * 256 + tid];
    if (tid < 16 * KK) {
        const int r = tid / KK, i = tid - r * KK;
        gl_sh[r][i] = bf2f(Zb[(size_t)(tok0 + r) * DIM_TOTAL + DIM_CONV + DIM_SKIP + i]);
    }
    __syncthreads();
    for (int r = 0; r < 16; ++r) {
        float g[KK];
        *(float4*)&g[0] = *(const float4*)&gl_sh[r][0];
        *(float4*)&g[4] = *(const float4*)&gl_sh[r][4];
        *(float4*)&g[8] = *(const float4*)&gl_sh[r][8];
        float s[6] = {0.f, 0.f, 0.f, 0.f, 0.f, 0.f};
        #pragma unroll
        for (int i = 0; i < KK; ++i)
            #pragma unroll
            for (int cb = 0; cb < 6; ++cb)
                s[cb] = fmaf(g[i], wreg[cb][i], s[cb]);
        #pragma unroll
        for (int cb = 0; cb < 6; ++cb)
            sigG[(size_t)(tok0 + r) * DGATE + cb * 256 + tid] = f2bf(sigm(s[cb]));
    }
}

// ---------------- bf16 MFMA GEMM (BK=32, 5 blocks/CU): C[M,Nreal] = A @ Bt^T ----------------
template <bool BF16OUT>
__launch_bounds__(256)
__global__ void mfma_gemm(const ushort_t* __restrict__ A, const ushort_t* __restrict__ Bt,
                          void* __restrict__ Cv, int Nreal, int K) {
    __shared__ ushort_t As[2][128 * 32];
    __shared__ ushort_t Bs[2][128 * 32];
    const int tid = threadIdx.x;
    const int lane = tid & 63, w = tid >> 6;
    const int m0 = blockIdx.x * 128, n0 = blockIdx.y * 128;
    const int wm = w & 1, wn = w >> 1;
    const int nkt = K >> 5;
    const int lrow = lane >> 2;          // 0..15
    const int lcol = (lane & 3) * 8;     // 0,8,16,24

    f32x4 acc[4][4] = {};

    auto stage = [&](int buf, int k0) {
        #pragma unroll
        for (int i = 0; i < 2; ++i) {
            const int seg = w * 2 + i;               // 0..7 (16 rows each)
            const int row = seg * 16 + lrow;
            gload_lds16(&A[(size_t)(m0 + row) * K + k0 + lcol], &As[buf][seg * 512]);
            gload_lds16(&Bt[(size_t)(n0 + row) * K + k0 + lcol], &Bs[buf][seg * 512]);
        }
    };

    stage(0, 0);
    for (int kt = 0; kt < nkt; ++kt) {
        const int cur = kt & 1;
        __syncthreads();
        if (kt + 1 < nkt) stage(cur ^ 1, (kt + 1) << 5);
        short8v a[4], b[4];
        #pragma unroll
        for (int i = 0; i < 4; ++i)
            a[i] = *(const short8v*)&As[cur][(wm * 64 + i * 16 + (lane & 15)) * 32 + (lane >> 4) * 8];
        #pragma unroll
        for (int j = 0; j < 4; ++j)
            b[j] = *(const short8v*)&Bs[cur][(wn * 64 + j * 16 + (lane & 15)) * 32 + (lane >> 4) * 8];
        #pragma unroll
        for (int i = 0; i < 4; ++i)
            #pragma unroll
            for (int j = 0; j < 4; ++j)
                acc[i][j] = __builtin_amdgcn_mfma_f32_16x16x32_bf16(a[i], b[j], acc[i][j], 0, 0, 0);
    }
    #pragma unroll
    for (int i = 0; i < 4; ++i) {
        const int rbase = m0 + wm * 64 + i * 16 + (lane >> 4) * 4;
        #pragma unroll
        for (int j = 0; j < 4; ++j) {
            const int col = n0 + wn * 64 + j * 16 + (lane & 15);
            if (col < Nreal) {
                #pragma unroll
                for (int r = 0; r < 4; ++r) {
                    if constexpr (BF16OUT)
                        ((ushort_t*)Cv)[(size_t)(rbase + r) * Nreal + col] = f2bf(acc[i][j][r]);
                    else
                        ((float*)Cv)[(size_t)(rbase + r) * Nreal + col] = acc[i][j][r];
                }
            }
        }
    }
}

// ---------------- gemm2 MFMA: per-k grouped GEMM with fused val*silu(gate) ----------------
__launch_bounds__(256)
__global__ void gemm2_mfma(const ushort_t* __restrict__ OCNb, const ushort_t* __restrict__ CskB,
                           const ushort_t* __restrict__ Btv, const ushort_t* __restrict__ Btg,
                           ushort_t* __restrict__ Y) {
    __shared__ ushort_t As[2][128 * 64];
    __shared__ ushort_t Bvs[2][64 * 64];
    __shared__ ushort_t Bgs[2][64 * 64];
    const int tid = threadIdx.x;
    const int lane = tid & 63, w = tid >> 6;
    const int m0 = blockIdx.x * 128;
    const int n0 = blockIdx.y * 64;
    const int k  = blockIdx.z;
    const int wm = w & 1, wn = w >> 1;
    const int lrow = lane >> 3;
    const int lcol = (lane & 7) * 8;
    const ushort_t* btv = Btv + (size_t)k * 192 * 320;
    const ushort_t* btg = Btg + (size_t)k * 192 * 320;

    f32x4 accV[4][2] = {};
    f32x4 accG[4][2] = {};

    auto stage = [&](int buf, int kt) {
        #pragma unroll
        for (int i = 0; i < 4; ++i) {
            const int seg = w * 4 + i;
            const int row = seg * 8 + lrow;
            const ushort_t* src = (kt < 2)
                ? OCNb + (size_t)(m0 + row) * DGATE + k * 128 + kt * 64 + lcol
                : CskB + (size_t)(m0 + row) * DIM_SKIP + (kt - 2) * 64 + lcol;
            gload_lds16(src, &As[buf][seg * 512]);
        }
        #pragma unroll
        for (int i = 0; i < 2; ++i) {
            const int seg = w * 2 + i;
            const int row = seg * 8 + lrow;
            gload_lds16(btv + (size_t)(n0 + row) * 320 + kt * 64 + lcol, &Bvs[buf][seg * 512]);
            gload_lds16(btg + (size_t)(n0 + row) * 320 + kt * 64 + lcol, &Bgs[buf][seg * 512]);
        }
    };

    stage(0, 0);
    for (int kt = 0; kt < 5; ++kt) {
        const int cur = kt & 1;
        __syncthreads();
        if (kt + 1 < 5) stage(cur ^ 1, kt + 1);
        #pragma unroll
        for (int kk = 0; kk < 2; ++kk) {
            short8v a[4], bv[2], bg[2];
            #pragma unroll
            for (int i = 0; i < 4; ++i)
                a[i] = *(const short8v*)&As[cur][(wm * 64 + i * 16 + (lane & 15)) * 64 + kk * 32 + (lane >> 4) * 8];
            #pragma unroll
            for (int j = 0; j < 2; ++j) {
                bv[j] = *(const short8v*)&Bvs[cur][(wn * 32 + j * 16 + (lane & 15)) * 64 + kk * 32 + (lane >> 4) * 8];
                bg[j] = *(const short8v*)&Bgs[cur][(wn * 32 + j * 16 + (lane & 15)) * 64 + kk * 32 + (lane >> 4) * 8];
            }
            #pragma unroll
            for (int i = 0; i < 4; ++i)
                #pragma unroll
                for (int j = 0; j < 2; ++j) {
                    accV[i][j] = __builtin_amdgcn_mfma_f32_16x16x32_bf16(a[i], bv[j], accV[i][j], 0, 0, 0);
                    accG[i][j] = __builtin_amdgcn_mfma_f32_16x16x32_bf16(a[i], bg[j], accG[i][j], 0, 0, 0);
                }
        }
    }
    #pragma unroll
    for (int i = 0; i < 4; ++i) {
        const int rbase = m0 + wm * 64 + i * 16 + (lane >> 4) * 4;
        #pragma unroll
        for (int j = 0; j < 2; ++j) {
            const int col = k * 192 + n0 + wn * 32 + j * 16 + (lane & 15);
            #pragma unroll
            for (int r = 0; r < 4; ++r) {
                const float g = accG[i][j][r];
                Y[(size_t)(rbase + r) * (KK * 3 * HH) + col] = f2bf(accV[i][j][r] * (g * sigm(g)));
            }
        }
    }
}

// ---------------- fused feature + scan: per (b,k,chunk32), 64 lanes = 64 heads ----------------
// acc layout TOKEN-MAJOR: acc[(b*LL+t)*KK + k][h] (float2); pcum[(b*LL+t)*KK + k].
__launch_bounds__(64)
__global__ void feat_scan(const ushort_t* __restrict__ Zb, const float* __restrict__ conv_w,
                          const float* __restrict__ wk, const float* __restrict__ theta_raw,
                          const float* __restrict__ dt_scale, const float* __restrict__ dt_bias,
                          const float* __restrict__ log_A, const float* __restrict__ phase_scale,
                          float2* __restrict__ acc, float* __restrict__ pcum,
                          float2* __restrict__ cend, float* __restrict__ cp) {
    const int blk = blockIdx.x;                  // (b*KK+k)*NCHUNK + chunk
    const int bk = blk / NCHUNK, chunk = blk - bk * NCHUNK;
    const int b = bk / KK, k = bk - b * KK;
    const int h = threadIdx.x;
    const int t0 = chunk * LCHUNK;
    const int cm_ch = k * HH + h;
    const int cs_ch = DIM_MEM + k;

    const float w0 = conv_w[0 * DIM_CONV + cm_ch];
    const float w1 = conv_w[1 * DIM_CONV + cm_ch];
    const float w2 = conv_w[2 * DIM_CONV + cm_ch];
    const float w3 = conv_w[3 * DIM_CONV + cm_ch];
    const float s0 = conv_w[0 * DIM_CONV + cs_ch];
    const float s1 = conv_w[1 * DIM_CONV + cs_ch];
    const float s2 = conv_w[2 * DIM_CONV + cs_ch];
    const float s3 = conv_w[3 * DIM_CONV + cs_ch];
    const float wkh = wk[h];
    const float th = 0.001f + (3.0f - 0.001f) * sigm(theta_raw[cm_ch]);
    const float ps = phase_scale[k];
    const float dts = dt_scale[k], dtb = dt_bias[k];
    const float eA = expf(log_A[k]);

    const size_t rowb = (size_t)b * LL;
    auto zm_at = [&](int t) -> float {
        return (t >= 0) ? bf2f(Zb[(rowb + t) * DIM_TOTAL + cm_ch]) : 0.f;
    };
    auto zs_at = [&](int t) -> float {
        return (t >= 0) ? bf2f(Zb[(rowb + t) * DIM_TOTAL + cs_ch]) : 0.f;
    };
    float zm3 = zm_at(t0 - 3), zm2 = zm_at(t0 - 2), zm1 = zm_at(t0 - 1);
    float zs3 = zs_at(t0 - 3), zs2 = zs_at(t0 - 2), zs1 = zs_at(t0 - 1);

    float are = 0.f, aim = 0.f, P = 1.f;
    #pragma unroll 4
    for (int tt = 0; tt < LCHUNK; ++tt) {
        const int t = t0 + tt;
        const float zm0 = bf2f(Zb[(rowb + t) * DIM_TOTAL + cm_ch]);
        const float zs0 = bf2f(Zb[(rowb + t) * DIM_TOTAL + cs_ch]);
        float cm = fmaf(w0, zm3, fmaf(w1, zm2, fmaf(w2, zm1, w3 * zm0)));
        float cs = fmaf(s0, zs3, fmaf(s1, zs2, fmaf(s2, zs1, s3 * zs0)));
        const float um = cm * sigm(cm);
        const float us = cs * sigm(cs);
        float ssq = um * um;
        #pragma unroll
        for (int off = 32; off > 0; off >>= 1) ssq += __shfl_xor(ssq, off);
        const float kval = um * rsqrtf(ssq * (1.0f / (float)HH) + 1e-6f) * wkh;
        float lin = fminf(fmaxf(fmaf(dts, us, dtb), -20.f), 20.f);
        float dt = fminf(fmaxf(softplus_fast(lin), 0.001f), 0.1f);
        const float Ad = fminf(fmaxf(-eA * dt, -20.f), 0.f);
        const float dec = __expf(Ad);
        const float ks = kval * ps;
        const float phi = ks / (1.0f + fabsf(ks)) * th;
        const float kvw = kval * dt;
        float sp, cq;
        __sincosf(phi, &sp, &cq);
        are = fmaf(dec, are, kvw * cq);
        aim = fmaf(dec, aim, kvw * sp);
        P *= dec;
        const size_t tokK = (rowb + t) * KK + k;
        acc[tokK * HH + h] = make_float2(are, aim);
        if (h == 0) pcum[tokK] = P;
        zm3 = zm2; zm2 = zm1; zm1 = zm0;
        zs3 = zs2; zs2 = zs1; zs1 = zs0;
    }
    cend[(size_t)blk * HH + h] = make_float2(are, aim);
    if (h == 0) cp[blk] = P;
}

// ---------------- scan phase B ----------------
__launch_bounds__(128)
__global__ void scan_b(const float* __restrict__ cend, const float* __restrict__ cp,
                       float* __restrict__ carry) {
    const int bk = blockIdx.x;
    const int c = threadIdx.x;
    float cur = 0.f;
    for (int ch = 0; ch < NCHUNK; ++ch) {
        const size_t idx = (size_t)bk * NCHUNK + ch;
        carry[idx * 128 + c] = cur;
        cur = fmaf(cp[idx], cur, cend[idx * 128 + c]);
    }
}

// ---------------- combine (slim): q-conv+rms, fixup, q-match, sigG apply, rms ----------------
// sigG aliases ocnB: all sigG reads complete (barrier) before ocnB writes. No __restrict__ on them.
__launch_bounds__(256)
__global__ void combine_kernel(const float2* __restrict__ acc, const float* __restrict__ pcum,
                               const float2* __restrict__ carry, const ushort_t* __restrict__ Zb,
                               const float* __restrict__ conv_w, const float* __restrict__ wq,
                               const float* __restrict__ wintG, const ushort_t* sigG,
                               const float* __restrict__ gn_weight,
                               ushort_t* ocnB, ushort_t* __restrict__ cskB) {
    __shared__ float q_sh[DIM_Q];
    __shared__ float g_sh[DGATE];
    __shared__ float red[8];
    const int tok = blockIdx.x;
    const int b = tok / LL, t = tok % LL;
    const int tid = threadIdx.x;
    const int chunk = t / LCHUNK;
    const size_t zrow = (size_t)tok * DIM_TOTAL;
    const size_t tokK = (size_t)tok * KK;

    if (tid < DIM_SKIP) cskB[(size_t)tok * DIM_SKIP + tid] = Zb[zrow + DIM_CONV + tid];

    // q = rms(silu(conv(q_raw)), 768) * wq
    float part = 0.f;
    float qv[3];
    #pragma unroll
    for (int it = 0; it < 3; ++it) {
        const int c = tid + it * 256;
        const int ch = DIM_MEMT + c;
        float s = 0.f;
        #pragma unroll
        for (int j = 0; j < KSZ; ++j) {
            const int tt2 = t + j - (KSZ - 1);
            if (tt2 >= 0)
                s = fmaf(conv_w[j * DIM_CONV + ch],
                         bf2f(Zb[((size_t)(b * LL + tt2)) * DIM_TOTAL + ch]), s);
        }
        const float u = s * sigm(s);
        qv[it] = u;
        part = fmaf(u, u, part);
    }
    const float qss = blockReduceSum256(part, red);
    const float qrs = rsqrtf(qss / (float)DIM_Q + 1e-6f);
    #pragma unroll
    for (int it = 0; it < 3; ++it) {
        const int c = tid + it * 256;
        q_sh[c] = qv[it] * qrs * wq[c];
    }
    __syncthreads();

    float part2 = 0.f;
    #pragma unroll
    for (int it = 0; it < 3; ++it) {
        const int p = tid + it * 256;        // p = k*64 + h -> acc[tokK*768 + p] contiguous
        const int k = p >> 6, h = p & 63;
        const int kq = k >> 1;
        const float pc = pcum[tokK + k];
        const float2 a2 = acc[tokK * HH + p];
        const float2 c2 = carry[((size_t)(b * KK + k) * NCHUNK + chunk) * HH + h];
        const float re = fmaf(pc, c2.x, a2.x);
        const float im = fmaf(pc, c2.y, a2.y);
        const float qre = q_sh[kq * 128 + 2 * h];
        const float qim = q_sh[kq * 128 + 2 * h + 1];
        const float wint = wintG[p];
        const float ore = (re * qre + im * qim) * wint;
        const float oim = (im * qre - re * qim) * wint;
        const int cre = k * 128 + h, cim = k * 128 + 64 + h;
        const float g_re = ore * bf2f(sigG[(size_t)tok * DGATE + cre]);
        const float g_im = oim * bf2f(sigG[(size_t)tok * DGATE + cim]);
        g_sh[cre] = g_re;
        g_sh[cim] = g_im;
        part2 = fmaf(g_re, g_re, part2);
        part2 = fmaf(g_im, g_im, part2);
    }
    const float ss = blockReduceSum256(part2, red);   // barrier: all sigG reads done
    const float rs = rsqrtf(ss / (float)DGATE + 1e-6f);
    __syncthreads();
    #pragma unroll
    for (int it = 0; it < 6; ++it) {
        const int c = tid + it * 256;
        ocnB[(size_t)tok * DGATE + c] = f2bf(g_sh[c] * rs * gn_weight[c]);
    }
}

// ---------------- launch ----------------
static inline size_t pass_need_bytes(int TP) {
    const size_t BP = (size_t)TP / LL;
    size_t total = 0;
    total += (size_t)TP * DIM_TOTAL * 2;            // Zb bf16
    total += (size_t)TP * KK * HH * 8;              // acc f32x2 (aliases WinT, then Y)
    total += (size_t)TP * KK * 4;                   // pcum
    total += BP * KK * NCHUNK * HH * 8;             // cend
    total += BP * KK * NCHUNK * 4;                  // cp
    total += BP * KK * NCHUNK * HH * 8;             // carry
    total += (size_t)TP * (DGATE + DIM_SKIP) * 2;   // ocnB(=sigG) + cskB (aliases xb)
    total += 8ull * 1024 * 1024;                    // WoutT + Btv + Btg + wint
    return total;
}

extern "C" void kernel_launch(void* const* d_in, const int* in_sizes, int n_in,
                              void* d_out, int out_size, void* d_ws, size_t ws_size,
                              hipStream_t stream) {
    const float* x           = (const float*)d_in[0];
    const float* W_in        = (const float*)d_in[1];
    const float* conv_w      = (const float*)d_in[2];
    const float* wk          = (const float*)d_in[3];
    const float* wq          = (const float*)d_in[4];
    const float* theta_raw   = (const float*)d_in[5];
    const float* w_int_raw   = (const float*)d_in[6];
    const float* dt_scale    = (const float*)d_in[7];
    const float* dt_bias     = (const float*)d_in[8];
    const float* log_A       = (const float*)d_in[9];
    const float* phase_scale = (const float*)d_in[10];
    const float* W_gate      = (const float*)d_in[11];
    const float* gn_weight   = (const float*)d_in[12];
    const float* W_readout   = (const float*)d_in[13];
    const float* W_skip      = (const float*)d_in[14];
    const float* W_out       = (const float*)d_in[15];
    float* out = (float*)d_out;

    int passes = 4;
    if (ws_size >= pass_need_bytes(TTOK))        passes = 1;
    else if (ws_size >= pass_need_bytes(TTOK/2)) passes = 2;

    const int BP = BB / passes;
    const int TP = BP * LL;

    char* p = (char*)d_ws;
    ushort_t* Zb   = (ushort_t*)p;               p += (size_t)TP * DIM_TOTAL * 2;
    char* accR     = p;
    float2* acc    = (float2*)p;                 p += (size_t)TP * KK * HH * 8;
    float* pcum    = (float*)p;                  p += (size_t)TP * KK * 4;
    float2* cendv  = (float2*)p;                 p += (size_t)BP * KK * NCHUNK * HH * 8;
    float* cp      = (float*)p;                  p += (size_t)BP * KK * NCHUNK * 4;
    float2* carry  = (float2*)p;                 p += (size_t)BP * KK * NCHUNK * HH * 8;
    char* ocnR     = p;
    ushort_t* ocnB = (ushort_t*)p;               p += (size_t)TP * DGATE * 2;
    ushort_t* cskB = (ushort_t*)p;               p += (size_t)TP * DIM_SKIP * 2;
    ushort_t* WoutT= (ushort_t*)p;               p += (size_t)768 * 2304 * 2;
    ushort_t* Btv  = (ushort_t*)p;               p += (size_t)KK * 192 * 320 * 2;
    ushort_t* Btg  = (ushort_t*)p;               p += (size_t)KK * 192 * 320 * 2;
    float* wintG   = (float*)p;                  p += (size_t)KK * HH * 4;
    // aliases (stream-serial lifetime reuse):
    ushort_t* xb   = (ushort_t*)ocnR;   // [TP][768] bf16, dead after GEMM1
    ushort_t* WinT = (ushort_t*)accR;   // [1792][768] bf16, dead after GEMM1
    ushort_t* Y    = (ushort_t*)accR;   // [TP][2304] bf16 (<= acc bytes), written after combine
    ushort_t* sigG = ocnB;              // gate sigmoids; consumed by combine BEFORE ocnB writes

    for (int pass = 0; pass < passes; ++pass) {
        const float* xp = x   + (size_t)pass * TP * DD;
        float*       op = out + (size_t)pass * TP * DD;

        // input-only preps (front-loaded)
        cast_bf16<<<1024, 256, 0, stream>>>(xp, xb, TP * DD / 4);
        transpose_cast<<<dim3(N1PAD / 32, DD / 32), dim3(32, 8), 0, stream>>>(
            W_in, WinT, DD, N1REAL, N1PAD);
        transpose_cast<<<dim3(DD / 32, (KK * 3 * HH) / 32), dim3(32, 8), 0, stream>>>(
            W_out, WoutT, KK * 3 * HH, DD, DD);
        prep_bt<<<dim3(KK, 192), 320, 0, stream>>>(W_readout, W_skip, Btv, Btg);
        prep_wint<<<3, 256, 0, stream>>>(w_int_raw, wintG);

        // 1. Zb = x @ W_in  (bf16 MFMA, bf16 output)  — also frees xb (ocnR region)
        mfma_gemm<true><<<dim3(TP / 128, N1PAD / 128), 256, 0, stream>>>(xb, WinT, Zb, N1REAL, DD);

        // 1b. sigG = sigmoid(gate_logits @ W_gate)  (writes into ocnB region)
        gate_gemm16<<<TP / 16, 256, 0, stream>>>(Zb, W_gate, sigG);

        // 2. fused conv+feat+scan (token-major acc/pcum)
        feat_scan<<<BP * KK * NCHUNK, 64, 0, stream>>>(Zb, conv_w, wk, theta_raw, dt_scale,
                                                       dt_bias, log_A, phase_scale,
                                                       acc, pcum, cendv, cp);

        // 3. carry propagation
        scan_b<<<BP * KK, 128, 0, stream>>>((const float*)cendv, cp, (float*)carry);

        // 4. combine (reads sigG, then overwrites same region as ocnB)
        combine_kernel<<<TP, 256, 0, stream>>>(acc, pcum, carry, Zb, conv_w, wq, wintG,
                                               sigG, gn_weight, ocnB, cskB);

        // 5. Y(bf16) = val*silu(gate) of grouped MFMA GEMM (readout + skip, K=320)
        gemm2_mfma<<<dim3(TP / 128, 3, KK), 256, 0, stream>>>(ocnB, cskB, Btv, Btg, Y);

        // 6. out = Y @ W_out  (bf16 MFMA, f32 output)
        mfma_gemm<false><<<dim3(TP / 128, DD / 128), 256, 0, stream>>>(Y, WoutT, op, DD, KK * 3 * HH);
    }
}

// Round 15
// 375.203 us; speedup vs baseline: 1.1781x; 1.0521x over previous
//
#include <hip/hip_runtime.h>
#include <hip/hip_bf16.h>
#include <cstdint>
#include <cstddef>

// ---------------- problem constants ----------------
#define BB 4
#define LL 4096
#define DD 768
#define KK 12
#define HH 64
#define KSZ 4
#define DIM_MEM 768
#define DIM_MEMT 780
#define DIM_Q 768
#define DIM_CONV 1548
#define DIM_SKIP 192
#define DIM_SWH 384
#define DIM_TOTAL 1752
#define TTOK (BB*LL)
#define NCHUNK 128
#define LCHUNK 32            // LL / NCHUNK
#define N1REAL 1752
#define N1PAD 1792
#define DGATE (KK*2*HH)      // 1536

typedef unsigned short ushort_t;
typedef __attribute__((ext_vector_type(8))) short short8v;   // 8 x bf16 (4 VGPRs)
typedef __attribute__((ext_vector_type(4))) float f32x4;

// ---------------- helpers ----------------
__device__ __forceinline__ float sigm(float x) {
    return __builtin_amdgcn_rcpf(1.0f + __expf(-x));
}
__device__ __forceinline__ float softplus_fast(float x) {
    return (x > 0.f) ? (x + __logf(1.0f + __expf(-x))) : __logf(1.0f + __expf(x));
}
__device__ __forceinline__ ushort_t f2bf(float f) {
    __hip_bfloat16 h = __float2bfloat16(f);
    return __builtin_bit_cast(ushort_t, h);
}
__device__ __forceinline__ float bf2f(ushort_t u) {
    const uint32_t i = ((uint32_t)u) << 16;
    return __builtin_bit_cast(float, i);
}
__device__ __forceinline__ float blockReduceSum256(float v, float* sbuf) {
    #pragma unroll
    for (int off = 32; off > 0; off >>= 1) v += __shfl_xor(v, off);
    const int wid = threadIdx.x >> 6;
    __syncthreads();
    if ((threadIdx.x & 63) == 0) sbuf[wid] = v;
    __syncthreads();
    return sbuf[0] + sbuf[1] + sbuf[2] + sbuf[3];
}
__device__ __forceinline__ void gload_lds16(const void* g, void* l) {
    __builtin_amdgcn_global_load_lds(
        (const __attribute__((address_space(1))) void*)g,
        (__attribute__((address_space(3))) void*)l, 16, 0, 0);
}

// ---------------- cast fp32 -> bf16 (vectorized) ----------------
__launch_bounds__(256)
__global__ void cast_bf16(const float* __restrict__ in, ushort_t* __restrict__ out, int n4) {
    const int stride = gridDim.x * 256;
    for (int i = blockIdx.x * 256 + threadIdx.x; i < n4; i += stride) {
        const float4 v = reinterpret_cast<const float4*>(in)[i];
        ushort4 o;
        o.x = f2bf(v.x); o.y = f2bf(v.y); o.z = f2bf(v.z); o.w = f2bf(v.w);
        reinterpret_cast<ushort4*>(out)[i] = o;
    }
}

// ---------------- transpose + cast: in[R][Cc] f32 -> out[Cpad][R] bf16 (zero pad) ----------------
__global__ void transpose_cast(const float* __restrict__ in, ushort_t* __restrict__ out,
                               int R, int Cc, int Cpad) {
    __shared__ float tile[32][33];
    const int tx = threadIdx.x, ty = threadIdx.y;
    const int c0 = blockIdx.x * 32, r0 = blockIdx.y * 32;
    #pragma unroll
    for (int rr = ty; rr < 32; rr += 8) {
        const int r = r0 + rr, c = c0 + tx;
        tile[rr][tx] = (r < R && c < Cc) ? in[(size_t)r * Cc + c] : 0.f;
    }
    __syncthreads();
    #pragma unroll
    for (int rr = ty; rr < 32; rr += 8) {
        const int c = c0 + rr, r = r0 + tx;
        if (c < Cpad && r < R)
            out[(size_t)c * R + r] = f2bf(tile[tx][rr]);
    }
}

// ---------------- build Bt for gemm2: Btv/Btg [12][192][320] bf16 ----------------
__global__ void prep_bt(const float* __restrict__ Wr, const float* __restrict__ Wskip,
                        ushort_t* __restrict__ Btv, ushort_t* __restrict__ Btg) {
    const int k = blockIdx.x, n = blockIdx.y, kk = threadIdx.x;   // block 320
    float v, g;
    if (kk < 128) {
        const size_t base = ((size_t)k * 128 + kk) * DIM_SWH;
        v = Wr[base + n];
        g = Wr[base + 192 + n];
    } else {
        const size_t base = (size_t)(kk - 128) * (KK * DIM_SWH) + (size_t)k * DIM_SWH;
        v = Wskip[base + n];
        g = Wskip[base + 192 + n];
    }
    const size_t o = ((size_t)k * 192 + n) * 320 + kk;
    Btv[o] = f2bf(v);
    Btg[o] = f2bf(g);
}

// ---------------- prep wint: wint[768] = exp(clamp(w_int_raw, -5, 5))  (accurate, runs once) ----------------
__global__ void prep_wint(const float* __restrict__ w_int_raw, float* __restrict__ wint) {
    const int i = blockIdx.x * 256 + threadIdx.x;
    if (i < KK * HH) {
        float wr = w_int_raw[i];
        wr = fminf(fmaxf(wr, -5.f), 5.f);
        wint[i] = expf(wr);
    }
}

// ---------------- gate GEMM: sigG[T,1536] = sigmoid(gate_logits[T,12] @ W_gate[12,1536]) ----------------
__launch_bounds__(256)
__global__ void gate_gemm16(const ushort_t* __restrict__ Zb, const float* __restrict__ W_gate,
                            ushort_t* sigG) {
    __shared__ float gl_sh[16][KK];
    const int tid = threadIdx.x;
    const int tok0 = blockIdx.x * 16;
    float wreg[6][KK];
    #pragma unroll
    for (int cb = 0; cb < 6; ++cb)
        #pragma unroll
        for (int i = 0; i < KK; ++i)
            wreg[cb][i] = W_gate[i * DGATE + cb * 256 + tid];
    if (tid < 16 * KK) {
        const int r = tid / KK, i = tid - r * KK;
        gl_sh[r][i] = bf2f(Zb[(size_t)(tok0 + r) * DIM_TOTAL + DIM_CONV + DIM_SKIP + i]);
    }
    __syncthreads();
    for (int r = 0; r < 16; ++r) {
        float g[KK];
        *(float4*)&g[0] = *(const float4*)&gl_sh[r][0];
        *(float4*)&g[4] = *(const float4*)&gl_sh[r][4];
        *(float4*)&g[8] = *(const float4*)&gl_sh[r][8];
        float s[6] = {0.f, 0.f, 0.f, 0.f, 0.f, 0.f};
        #pragma unroll
        for (int i = 0; i < KK; ++i)
            #pragma unroll
            for (int cb = 0; cb < 6; ++cb)
                s[cb] = fmaf(g[i], wreg[cb][i], s[cb]);
        #pragma unroll
        for (int cb = 0; cb < 6; ++cb)
            sigG[(size_t)(tok0 + r) * DGATE + cb * 256 + tid] = f2bf(sigm(s[cb]));
    }
}

// ---------------- bf16 MFMA GEMM (BK=32, 5 blocks/CU): C[M,Nreal] = A @ Bt^T ----------------
template <bool BF16OUT>
__launch_bounds__(256)
__global__ void mfma_gemm(const ushort_t* __restrict__ A, const ushort_t* __restrict__ Bt,
                          void* __restrict__ Cv, int Nreal, int K) {
    __shared__ ushort_t As[2][128 * 32];
    __shared__ ushort_t Bs[2][128 * 32];
    const int tid = threadIdx.x;
    const int lane = tid & 63, w = tid >> 6;
    const int m0 = blockIdx.x * 128, n0 = blockIdx.y * 128;
    const int wm = w & 1, wn = w >> 1;
    const int nkt = K >> 5;
    const int lrow = lane >> 2;          // 0..15
    const int lcol = (lane & 3) * 8;     // 0,8,16,24

    f32x4 acc[4][4] = {};

    auto stage = [&](int buf, int k0) {
        #pragma unroll
        for (int i = 0; i < 2; ++i) {
            const int seg = w * 2 + i;               // 0..7 (16 rows each)
            const int row = seg * 16 + lrow;
            gload_lds16(&A[(size_t)(m0 + row) * K + k0 + lcol], &As[buf][seg * 512]);
            gload_lds16(&Bt[(size_t)(n0 + row) * K + k0 + lcol], &Bs[buf][seg * 512]);
        }
    };

    stage(0, 0);
    for (int kt = 0; kt < nkt; ++kt) {
        const int cur = kt & 1;
        __syncthreads();
        if (kt + 1 < nkt) stage(cur ^ 1, (kt + 1) << 5);
        short8v a[4], b[4];
        #pragma unroll
        for (int i = 0; i < 4; ++i)
            a[i] = *(const short8v*)&As[cur][(wm * 64 + i * 16 + (lane & 15)) * 32 + (lane >> 4) * 8];
        #pragma unroll
        for (int j = 0; j < 4; ++j)
            b[j] = *(const short8v*)&Bs[cur][(wn * 64 + j * 16 + (lane & 15)) * 32 + (lane >> 4) * 8];
        #pragma unroll
        for (int i = 0; i < 4; ++i)
            #pragma unroll
            for (int j = 0; j < 4; ++j)
                acc[i][j] = __builtin_amdgcn_mfma_f32_16x16x32_bf16(a[i], b[j], acc[i][j], 0, 0, 0);
    }
    #pragma unroll
    for (int i = 0; i < 4; ++i) {
        const int rbase = m0 + wm * 64 + i * 16 + (lane >> 4) * 4;
        #pragma unroll
        for (int j = 0; j < 4; ++j) {
            const int col = n0 + wn * 64 + j * 16 + (lane & 15);
            if (col < Nreal) {
                #pragma unroll
                for (int r = 0; r < 4; ++r) {
                    if constexpr (BF16OUT)
                        ((ushort_t*)Cv)[(size_t)(rbase + r) * Nreal + col] = f2bf(acc[i][j][r]);
                    else
                        ((float*)Cv)[(size_t)(rbase + r) * Nreal + col] = acc[i][j][r];
                }
            }
        }
    }
}

// ---------------- gemm2 MFMA (BK=32, 32 KB LDS): per-k grouped GEMM, fused val*silu(gate) ----------------
// grid (M/128, 192/64, 12), block 256. K = 320 = 10 steps of 32 (4 over OCN_k, 6 over cskip).
__launch_bounds__(256)
__global__ void gemm2_mfma(const ushort_t* __restrict__ OCNb, const ushort_t* __restrict__ CskB,
                           const ushort_t* __restrict__ Btv, const ushort_t* __restrict__ Btg,
                           ushort_t* __restrict__ Y) {
    __shared__ ushort_t As[2][128 * 32];
    __shared__ ushort_t Bvs[2][64 * 32];
    __shared__ ushort_t Bgs[2][64 * 32];
    const int tid = threadIdx.x;
    const int lane = tid & 63, w = tid >> 6;
    const int m0 = blockIdx.x * 128;
    const int n0 = blockIdx.y * 64;
    const int k  = blockIdx.z;
    const int wm = w & 1, wn = w >> 1;
    const int lrow = lane >> 2;          // 0..15
    const int lcol = (lane & 3) * 8;     // 0,8,16,24
    const ushort_t* btv = Btv + (size_t)k * 192 * 320;
    const ushort_t* btg = Btg + (size_t)k * 192 * 320;

    f32x4 accV[4][2] = {};
    f32x4 accG[4][2] = {};

    auto stage = [&](int buf, int kt) {
        #pragma unroll
        for (int i = 0; i < 2; ++i) {
            const int seg = w * 2 + i;               // 0..7 (16 rows each)
            const int row = seg * 16 + lrow;         // 0..127
            const ushort_t* src = (kt < 4)
                ? OCNb + (size_t)(m0 + row) * DGATE + k * 128 + kt * 32 + lcol
                : CskB + (size_t)(m0 + row) * DIM_SKIP + (kt - 4) * 32 + lcol;
            gload_lds16(src, &As[buf][seg * 512]);
        }
        {
            const int seg = w;                       // 0..3 (16 rows each)
            const int row = seg * 16 + lrow;         // 0..63
            gload_lds16(btv + (size_t)(n0 + row) * 320 + kt * 32 + lcol, &Bvs[buf][seg * 512]);
            gload_lds16(btg + (size_t)(n0 + row) * 320 + kt * 32 + lcol, &Bgs[buf][seg * 512]);
        }
    };

    stage(0, 0);
    for (int kt = 0; kt < 10; ++kt) {
        const int cur = kt & 1;
        __syncthreads();
        if (kt + 1 < 10) stage(cur ^ 1, kt + 1);
        short8v a[4], bv[2], bg[2];
        #pragma unroll
        for (int i = 0; i < 4; ++i)
            a[i] = *(const short8v*)&As[cur][(wm * 64 + i * 16 + (lane & 15)) * 32 + (lane >> 4) * 8];
        #pragma unroll
        for (int j = 0; j < 2; ++j) {
            bv[j] = *(const short8v*)&Bvs[cur][(wn * 32 + j * 16 + (lane & 15)) * 32 + (lane >> 4) * 8];
            bg[j] = *(const short8v*)&Bgs[cur][(wn * 32 + j * 16 + (lane & 15)) * 32 + (lane >> 4) * 8];
        }
        #pragma unroll
        for (int i = 0; i < 4; ++i)
            #pragma unroll
            for (int j = 0; j < 2; ++j) {
                accV[i][j] = __builtin_amdgcn_mfma_f32_16x16x32_bf16(a[i], bv[j], accV[i][j], 0, 0, 0);
                accG[i][j] = __builtin_amdgcn_mfma_f32_16x16x32_bf16(a[i], bg[j], accG[i][j], 0, 0, 0);
            }
    }
    #pragma unroll
    for (int i = 0; i < 4; ++i) {
        const int rbase = m0 + wm * 64 + i * 16 + (lane >> 4) * 4;
        #pragma unroll
        for (int j = 0; j < 2; ++j) {
            const int col = k * 192 + n0 + wn * 32 + j * 16 + (lane & 15);
            #pragma unroll
            for (int r = 0; r < 4; ++r) {
                const float g = accG[i][j][r];
                Y[(size_t)(rbase + r) * (KK * 3 * HH) + col] = f2bf(accV[i][j][r] * (g * sigm(g)));
            }
        }
    }
}

// ---------------- fused feature + scan: per (b,k,chunk32), 64 lanes = 64 heads ----------------
// acc layout TOKEN-MAJOR: acc[(b*LL+t)*KK + k][h] (float2); pcum[(b*LL+t)*KK + k].
__launch_bounds__(64)
__global__ void feat_scan(const ushort_t* __restrict__ Zb, const float* __restrict__ conv_w,
                          const float* __restrict__ wk, const float* __restrict__ theta_raw,
                          const float* __restrict__ dt_scale, const float* __restrict__ dt_bias,
                          const float* __restrict__ log_A, const float* __restrict__ phase_scale,
                          float2* __restrict__ acc, float* __restrict__ pcum,
                          float2* __restrict__ cend, float* __restrict__ cp) {
    const int blk = blockIdx.x;                  // (b*KK+k)*NCHUNK + chunk
    const int bk = blk / NCHUNK, chunk = blk - bk * NCHUNK;
    const int b = bk / KK, k = bk - b * KK;
    const int h = threadIdx.x;
    const int t0 = chunk * LCHUNK;
    const int cm_ch = k * HH + h;
    const int cs_ch = DIM_MEM + k;

    const float w0 = conv_w[0 * DIM_CONV + cm_ch];
    const float w1 = conv_w[1 * DIM_CONV + cm_ch];
    const float w2 = conv_w[2 * DIM_CONV + cm_ch];
    const float w3 = conv_w[3 * DIM_CONV + cm_ch];
    const float s0 = conv_w[0 * DIM_CONV + cs_ch];
    const float s1 = conv_w[1 * DIM_CONV + cs_ch];
    const float s2 = conv_w[2 * DIM_CONV + cs_ch];
    const float s3 = conv_w[3 * DIM_CONV + cs_ch];
    const float wkh = wk[h];
    const float th = 0.001f + (3.0f - 0.001f) * sigm(theta_raw[cm_ch]);
    const float ps = phase_scale[k];
    const float dts = dt_scale[k], dtb = dt_bias[k];
    const float eA = expf(log_A[k]);

    const size_t rowb = (size_t)b * LL;
    auto zm_at = [&](int t) -> float {
        return (t >= 0) ? bf2f(Zb[(rowb + t) * DIM_TOTAL + cm_ch]) : 0.f;
    };
    auto zs_at = [&](int t) -> float {
        return (t >= 0) ? bf2f(Zb[(rowb + t) * DIM_TOTAL + cs_ch]) : 0.f;
    };
    float zm3 = zm_at(t0 - 3), zm2 = zm_at(t0 - 2), zm1 = zm_at(t0 - 1);
    float zs3 = zs_at(t0 - 3), zs2 = zs_at(t0 - 2), zs1 = zs_at(t0 - 1);

    float are = 0.f, aim = 0.f, P = 1.f;
    #pragma unroll 4
    for (int tt = 0; tt < LCHUNK; ++tt) {
        const int t = t0 + tt;
        const float zm0 = bf2f(Zb[(rowb + t) * DIM_TOTAL + cm_ch]);
        const float zs0 = bf2f(Zb[(rowb + t) * DIM_TOTAL + cs_ch]);
        float cm = fmaf(w0, zm3, fmaf(w1, zm2, fmaf(w2, zm1, w3 * zm0)));
        float cs = fmaf(s0, zs3, fmaf(s1, zs2, fmaf(s2, zs1, s3 * zs0)));
        const float um = cm * sigm(cm);
        const float us = cs * sigm(cs);
        float ssq = um * um;
        #pragma unroll
        for (int off = 32; off > 0; off >>= 1) ssq += __shfl_xor(ssq, off);
        const float kval = um * rsqrtf(ssq * (1.0f / (float)HH) + 1e-6f) * wkh;
        float lin = fminf(fmaxf(fmaf(dts, us, dtb), -20.f), 20.f);
        float dt = fminf(fmaxf(softplus_fast(lin), 0.001f), 0.1f);
        const float Ad = fminf(fmaxf(-eA * dt, -20.f), 0.f);
        const float dec = __expf(Ad);
        const float ks = kval * ps;
        const float phi = ks / (1.0f + fabsf(ks)) * th;
        const float kvw = kval * dt;
        float sp, cq;
        __sincosf(phi, &sp, &cq);
        are = fmaf(dec, are, kvw * cq);
        aim = fmaf(dec, aim, kvw * sp);
        P *= dec;
        const size_t tokK = (rowb + t) * KK + k;
        acc[tokK * HH + h] = make_float2(are, aim);
        if (h == 0) pcum[tokK] = P;
        zm3 = zm2; zm2 = zm1; zm1 = zm0;
        zs3 = zs2; zs2 = zs1; zs1 = zs0;
    }
    cend[(size_t)blk * HH + h] = make_float2(are, aim);
    if (h == 0) cp[blk] = P;
}

// ---------------- scan phase B ----------------
__launch_bounds__(128)
__global__ void scan_b(const float* __restrict__ cend, const float* __restrict__ cp,
                       float* __restrict__ carry) {
    const int bk = blockIdx.x;
    const int c = threadIdx.x;
    float cur = 0.f;
    for (int ch = 0; ch < NCHUNK; ++ch) {
        const size_t idx = (size_t)bk * NCHUNK + ch;
        carry[idx * 128 + c] = cur;
        cur = fmaf(cp[idx], cur, cend[idx * 128 + c]);
    }
}

// ---------------- combine (slim): q-conv+rms, fixup, q-match, sigG apply, rms ----------------
__launch_bounds__(256)
__global__ void combine_kernel(const float2* __restrict__ acc, const float* __restrict__ pcum,
                               const float2* __restrict__ carry, const ushort_t* __restrict__ Zb,
                               const float* __restrict__ conv_w, const float* __restrict__ wq,
                               const float* __restrict__ wintG, const ushort_t* sigG,
                               const float* __restrict__ gn_weight,
                               ushort_t* ocnB, ushort_t* __restrict__ cskB) {
    __shared__ float q_sh[DIM_Q];
    __shared__ float g_sh[DGATE];
    __shared__ float red[8];
    const int tok = blockIdx.x;
    const int b = tok / LL, t = tok % LL;
    const int tid = threadIdx.x;
    const int chunk = t / LCHUNK;
    const size_t zrow = (size_t)tok * DIM_TOTAL;
    const size_t tokK = (size_t)tok * KK;

    if (tid < DIM_SKIP) cskB[(size_t)tok * DIM_SKIP + tid] = Zb[zrow + DIM_CONV + tid];

    float part = 0.f;
    float qv[3];
    #pragma unroll
    for (int it = 0; it < 3; ++it) {
        const int c = tid + it * 256;
        const int ch = DIM_MEMT + c;
        float s = 0.f;
        #pragma unroll
        for (int j = 0; j < KSZ; ++j) {
            const int tt2 = t + j - (KSZ - 1);
            if (tt2 >= 0)
                s = fmaf(conv_w[j * DIM_CONV + ch],
                         bf2f(Zb[((size_t)(b * LL + tt2)) * DIM_TOTAL + ch]), s);
        }
        const float u = s * sigm(s);
        qv[it] = u;
        part = fmaf(u, u, part);
    }
    const float qss = blockReduceSum256(part, red);
    const float qrs = rsqrtf(qss / (float)DIM_Q + 1e-6f);
    #pragma unroll
    for (int it = 0; it < 3; ++it) {
        const int c = tid + it * 256;
        q_sh[c] = qv[it] * qrs * wq[c];
    }
    __syncthreads();

    float part2 = 0.f;
    #pragma unroll
    for (int it = 0; it < 3; ++it) {
        const int p = tid + it * 256;
        const int k = p >> 6, h = p & 63;
        const int kq = k >> 1;
        const float pc = pcum[tokK + k];
        const float2 a2 = acc[tokK * HH + p];
        const float2 c2 = carry[((size_t)(b * KK + k) * NCHUNK + chunk) * HH + h];
        const float re = fmaf(pc, c2.x, a2.x);
        const float im = fmaf(pc, c2.y, a2.y);
        const float qre = q_sh[kq * 128 + 2 * h];
        const float qim = q_sh[kq * 128 + 2 * h + 1];
        const float wint = wintG[p];
        const float ore = (re * qre + im * qim) * wint;
        const float oim = (im * qre - re * qim) * wint;
        const int cre = k * 128 + h, cim = k * 128 + 64 + h;
        const float g_re = ore * bf2f(sigG[(size_t)tok * DGATE + cre]);
        const float g_im = oim * bf2f(sigG[(size_t)tok * DGATE + cim]);
        g_sh[cre] = g_re;
        g_sh[cim] = g_im;
        part2 = fmaf(g_re, g_re, part2);
        part2 = fmaf(g_im, g_im, part2);
    }
    const float ss = blockReduceSum256(part2, red);   // barrier: all sigG reads done
    const float rs = rsqrtf(ss / (float)DGATE + 1e-6f);
    __syncthreads();
    #pragma unroll
    for (int it = 0; it < 6; ++it) {
        const int c = tid + it * 256;
        ocnB[(size_t)tok * DGATE + c] = f2bf(g_sh[c] * rs * gn_weight[c]);
    }
}

// ---------------- launch ----------------
static inline size_t pass_need_bytes(int TP) {
    const size_t BP = (size_t)TP / LL;
    size_t total = 0;
    total += (size_t)TP * DIM_TOTAL * 2;            // Zb bf16
    total += (size_t)TP * KK * HH * 8;              // acc f32x2 (aliases WinT, then Y)
    total += (size_t)TP * KK * 4;                   // pcum
    total += BP * KK * NCHUNK * HH * 8;             // cend
    total += BP * KK * NCHUNK * 4;                  // cp
    total += BP * KK * NCHUNK * HH * 8;             // carry
    total += (size_t)TP * (DGATE + DIM_SKIP) * 2;   // ocnB(=sigG) + cskB (aliases xb)
    total += 8ull * 1024 * 1024;                    // WoutT + Btv + Btg + wint
    return total;
}

extern "C" void kernel_launch(void* const* d_in, const int* in_sizes, int n_in,
                              void* d_out, int out_size, void* d_ws, size_t ws_size,
                              hipStream_t stream) {
    const float* x           = (const float*)d_in[0];
    const float* W_in        = (const float*)d_in[1];
    const float* conv_w      = (const float*)d_in[2];
    const float* wk          = (const float*)d_in[3];
    const float* wq          = (const float*)d_in[4];
    const float* theta_raw   = (const float*)d_in[5];
    const float* w_int_raw   = (const float*)d_in[6];
    const float* dt_scale    = (const float*)d_in[7];
    const float* dt_bias     = (const float*)d_in[8];
    const float* log_A       = (const float*)d_in[9];
    const float* phase_scale = (const float*)d_in[10];
    const float* W_gate      = (const float*)d_in[11];
    const float* gn_weight   = (const float*)d_in[12];
    const float* W_readout   = (const float*)d_in[13];
    const float* W_skip      = (const float*)d_in[14];
    const float* W_out       = (const float*)d_in[15];
    float* out = (float*)d_out;

    int passes = 4;
    if (ws_size >= pass_need_bytes(TTOK))        passes = 1;
    else if (ws_size >= pass_need_bytes(TTOK/2)) passes = 2;

    const int BP = BB / passes;
    const int TP = BP * LL;

    char* p = (char*)d_ws;
    ushort_t* Zb   = (ushort_t*)p;               p += (size_t)TP * DIM_TOTAL * 2;
    char* accR     = p;
    float2* acc    = (float2*)p;                 p += (size_t)TP * KK * HH * 8;
    float* pcum    = (float*)p;                  p += (size_t)TP * KK * 4;
    float2* cendv  = (float2*)p;                 p += (size_t)BP * KK * NCHUNK * HH * 8;
    float* cp      = (float*)p;                  p += (size_t)BP * KK * NCHUNK * 4;
    float2* carry  = (float2*)p;                 p += (size_t)BP * KK * NCHUNK * HH * 8;
    char* ocnR     = p;
    ushort_t* ocnB = (ushort_t*)p;               p += (size_t)TP * DGATE * 2;
    ushort_t* cskB = (ushort_t*)p;               p += (size_t)TP * DIM_SKIP * 2;
    ushort_t* WoutT= (ushort_t*)p;               p += (size_t)768 * 2304 * 2;
    ushort_t* Btv  = (ushort_t*)p;               p += (size_t)KK * 192 * 320 * 2;
    ushort_t* Btg  = (ushort_t*)p;               p += (size_t)KK * 192 * 320 * 2;
    float* wintG   = (float*)p;                  p += (size_t)KK * HH * 4;
    // aliases (stream-serial lifetime reuse):
    ushort_t* xb   = (ushort_t*)ocnR;   // [TP][768] bf16, dead after GEMM1
    ushort_t* WinT = (ushort_t*)accR;   // [1792][768] bf16, dead after GEMM1
    ushort_t* Y    = (ushort_t*)accR;   // [TP][2304] bf16 (<= acc bytes), written after combine
    ushort_t* sigG = ocnB;              // gate sigmoids; consumed by combine BEFORE ocnB writes

    for (int pass = 0; pass < passes; ++pass) {
        const float* xp = x   + (size_t)pass * TP * DD;
        float*       op = out + (size_t)pass * TP * DD;

        // input-only preps (front-loaded)
        cast_bf16<<<1024, 256, 0, stream>>>(xp, xb, TP * DD / 4);
        transpose_cast<<<dim3(N1PAD / 32, DD / 32), dim3(32, 8), 0, stream>>>(
            W_in, WinT, DD, N1REAL, N1PAD);
        transpose_cast<<<dim3(DD / 32, (KK * 3 * HH) / 32), dim3(32, 8), 0, stream>>>(
            W_out, WoutT, KK * 3 * HH, DD, DD);
        prep_bt<<<dim3(KK, 192), 320, 0, stream>>>(W_readout, W_skip, Btv, Btg);
        prep_wint<<<3, 256, 0, stream>>>(w_int_raw, wintG);

        // 1. Zb = x @ W_in  (bf16 MFMA, bf16 output)
        mfma_gemm<true><<<dim3(TP / 128, N1PAD / 128), 256, 0, stream>>>(xb, WinT, Zb, N1REAL, DD);

        // 1b. sigG = sigmoid(gate_logits @ W_gate)
        gate_gemm16<<<TP / 16, 256, 0, stream>>>(Zb, W_gate, sigG);

        // 2. fused conv+feat+scan (token-major acc/pcum)
        feat_scan<<<BP * KK * NCHUNK, 64, 0, stream>>>(Zb, conv_w, wk, theta_raw, dt_scale,
                                                       dt_bias, log_A, phase_scale,
                                                       acc, pcum, cendv, cp);

        // 3. carry propagation
        scan_b<<<BP * KK, 128, 0, stream>>>((const float*)cendv, cp, (float*)carry);

        // 4. combine (reads sigG, then overwrites same region as ocnB)
        combine_kernel<<<TP, 256, 0, stream>>>(acc, pcum, carry, Zb, conv_w, wq, wintG,
                                               sigG, gn_weight, ocnB, cskB);

        // 5. Y(bf16) = val*silu(gate) of grouped MFMA GEMM (readout + skip, K=320, BK=32)
        gemm2_mfma<<<dim3(TP / 128, 3, KK), 256, 0, stream>>>(ocnB, cskB, Btv, Btg, Y);

        // 6. out = Y @ W_out  (bf16 MFMA, f32 output)
        mfma_gemm<false><<<dim3(TP / 128, DD / 128), 256, 0, stream>>>(Y, WoutT, op, DD, KK * 3 * HH);
    }
}

// Round 16
// 367.690 us; speedup vs baseline: 1.2022x; 1.0204x over previous
//
#include <hip/hip_runtime.h>
#include <hip/hip_bf16.h>
#include <cstdint>
#include <cstddef>

// ---------------- problem constants ----------------
#define BB 4
#define LL 4096
#define DD 768
#define KK 12
#define HH 64
#define KSZ 4
#define DIM_MEM 768
#define DIM_MEMT 780
#define DIM_Q 768
#define DIM_CONV 1548
#define DIM_SKIP 192
#define DIM_SWH 384
#define DIM_TOTAL 1752
#define TTOK (BB*LL)
#define NCHUNK 128
#define LCHUNK 32            // LL / NCHUNK
#define N1REAL 1752
#define N1PAD 1792
#define DGATE (KK*2*HH)      // 1536

typedef unsigned short ushort_t;
typedef __attribute__((ext_vector_type(8))) short short8v;   // 8 x bf16 (4 VGPRs)
typedef __attribute__((ext_vector_type(4))) float f32x4;

// ---------------- helpers ----------------
__device__ __forceinline__ float sigm(float x) {
    return __builtin_amdgcn_rcpf(1.0f + __expf(-x));
}
__device__ __forceinline__ float softplus_fast(float x) {
    return (x > 0.f) ? (x + __logf(1.0f + __expf(-x))) : __logf(1.0f + __expf(x));
}
__device__ __forceinline__ ushort_t f2bf(float f) {
    __hip_bfloat16 h = __float2bfloat16(f);
    return __builtin_bit_cast(ushort_t, h);
}
__device__ __forceinline__ float bf2f(ushort_t u) {
    const uint32_t i = ((uint32_t)u) << 16;
    return __builtin_bit_cast(float, i);
}
__device__ __forceinline__ float blockReduceSum256(float v, float* sbuf) {
    #pragma unroll
    for (int off = 32; off > 0; off >>= 1) v += __shfl_xor(v, off);
    const int wid = threadIdx.x >> 6;
    __syncthreads();
    if ((threadIdx.x & 63) == 0) sbuf[wid] = v;
    __syncthreads();
    return sbuf[0] + sbuf[1] + sbuf[2] + sbuf[3];
}
__device__ __forceinline__ void gload_lds16(const void* g, void* l) {
    __builtin_amdgcn_global_load_lds(
        (const __attribute__((address_space(1))) void*)g,
        (__attribute__((address_space(3))) void*)l, 16, 0, 0);
}

// ---------------- cast fp32 -> bf16 (vectorized) ----------------
__launch_bounds__(256)
__global__ void cast_bf16(const float* __restrict__ in, ushort_t* __restrict__ out, int n4) {
    const int stride = gridDim.x * 256;
    for (int i = blockIdx.x * 256 + threadIdx.x; i < n4; i += stride) {
        const float4 v = reinterpret_cast<const float4*>(in)[i];
        ushort4 o;
        o.x = f2bf(v.x); o.y = f2bf(v.y); o.z = f2bf(v.z); o.w = f2bf(v.w);
        reinterpret_cast<ushort4*>(out)[i] = o;
    }
}

// ---------------- transpose + cast: in[R][Cc] f32 -> out[Cpad][R] bf16 (zero pad) ----------------
__global__ void transpose_cast(const float* __restrict__ in, ushort_t* __restrict__ out,
                               int R, int Cc, int Cpad) {
    __shared__ float tile[32][33];
    const int tx = threadIdx.x, ty = threadIdx.y;
    const int c0 = blockIdx.x * 32, r0 = blockIdx.y * 32;
    #pragma unroll
    for (int rr = ty; rr < 32; rr += 8) {
        const int r = r0 + rr, c = c0 + tx;
        tile[rr][tx] = (r < R && c < Cc) ? in[(size_t)r * Cc + c] : 0.f;
    }
    __syncthreads();
    #pragma unroll
    for (int rr = ty; rr < 32; rr += 8) {
        const int c = c0 + rr, r = r0 + tx;
        if (c < Cpad && r < R)
            out[(size_t)c * R + r] = f2bf(tile[tx][rr]);
    }
}

// ---------------- build Bt for gemm2: Btv/Btg [12][192][320] bf16 ----------------
__global__ void prep_bt(const float* __restrict__ Wr, const float* __restrict__ Wskip,
                        ushort_t* __restrict__ Btv, ushort_t* __restrict__ Btg) {
    const int k = blockIdx.x, n = blockIdx.y, kk = threadIdx.x;   // block 320
    float v, g;
    if (kk < 128) {
        const size_t base = ((size_t)k * 128 + kk) * DIM_SWH;
        v = Wr[base + n];
        g = Wr[base + 192 + n];
    } else {
        const size_t base = (size_t)(kk - 128) * (KK * DIM_SWH) + (size_t)k * DIM_SWH;
        v = Wskip[base + n];
        g = Wskip[base + 192 + n];
    }
    const size_t o = ((size_t)k * 192 + n) * 320 + kk;
    Btv[o] = f2bf(v);
    Btg[o] = f2bf(g);
}

// ---------------- prep wint: wint[768] = exp(clamp(w_int_raw, -5, 5))  (accurate, runs once) ----------------
__global__ void prep_wint(const float* __restrict__ w_int_raw, float* __restrict__ wint) {
    const int i = blockIdx.x * 256 + threadIdx.x;
    if (i < KK * HH) {
        float wr = w_int_raw[i];
        wr = fminf(fmaxf(wr, -5.f), 5.f);
        wint[i] = expf(wr);
    }
}

// ---------------- gate GEMM: sigG[T,1536] = sigmoid(gate_logits[T,12] @ W_gate[12,1536]) ----------------
__launch_bounds__(256)
__global__ void gate_gemm16(const ushort_t* __restrict__ Zb, const float* __restrict__ W_gate,
                            ushort_t* sigG) {
    __shared__ float gl_sh[16][KK];
    const int tid = threadIdx.x;
    const int tok0 = blockIdx.x * 16;
    float wreg[6][KK];
    #pragma unroll
    for (int cb = 0; cb < 6; ++cb)
        #pragma unroll
        for (int i = 0; i < KK; ++i)
            wreg[cb][i] = W_gate[i * DGATE + cb * 256 + tid];
    if (tid < 16 * KK) {
        const int r = tid / KK, i = tid - r * KK;
        gl_sh[r][i] = bf2f(Zb[(size_t)(tok0 + r) * DIM_TOTAL + DIM_CONV + DIM_SKIP + i]);
    }
    __syncthreads();
    for (int r = 0; r < 16; ++r) {
        float g[KK];
        *(float4*)&g[0] = *(const float4*)&gl_sh[r][0];
        *(float4*)&g[4] = *(const float4*)&gl_sh[r][4];
        *(float4*)&g[8] = *(const float4*)&gl_sh[r][8];
        float s[6] = {0.f, 0.f, 0.f, 0.f, 0.f, 0.f};
        #pragma unroll
        for (int i = 0; i < KK; ++i)
            #pragma unroll
            for (int cb = 0; cb < 6; ++cb)
                s[cb] = fmaf(g[i], wreg[cb][i], s[cb]);
        #pragma unroll
        for (int cb = 0; cb < 6; ++cb)
            sigG[(size_t)(tok0 + r) * DGATE + cb * 256 + tid] = f2bf(sigm(s[cb]));
    }
}

// ---------------- bf16 MFMA GEMM (BK=32, 32 KB LDS): C[M,Nreal] = A @ Bt^T ----------------
template <bool BF16OUT>
__launch_bounds__(256)
__global__ void mfma_gemm(const ushort_t* __restrict__ A, const ushort_t* __restrict__ Bt,
                          void* __restrict__ Cv, int Nreal, int K) {
    __shared__ ushort_t As[2][128 * 32];
    __shared__ ushort_t Bs[2][128 * 32];
    const int tid = threadIdx.x;
    const int lane = tid & 63, w = tid >> 6;
    const int m0 = blockIdx.x * 128, n0 = blockIdx.y * 128;
    const int wm = w & 1, wn = w >> 1;
    const int nkt = K >> 5;
    const int lrow = lane >> 2;          // 0..15
    const int lcol = (lane & 3) * 8;     // 0,8,16,24

    f32x4 acc[4][4] = {};

    auto stage = [&](int buf, int k0) {
        #pragma unroll
        for (int i = 0; i < 2; ++i) {
            const int seg = w * 2 + i;               // 0..7 (16 rows each)
            const int row = seg * 16 + lrow;
            gload_lds16(&A[(size_t)(m0 + row) * K + k0 + lcol], &As[buf][seg * 512]);
            gload_lds16(&Bt[(size_t)(n0 + row) * K + k0 + lcol], &Bs[buf][seg * 512]);
        }
    };

    stage(0, 0);
    for (int kt = 0; kt < nkt; ++kt) {
        const int cur = kt & 1;
        __syncthreads();
        if (kt + 1 < nkt) stage(cur ^ 1, (kt + 1) << 5);
        short8v a[4], b[4];
        #pragma unroll
        for (int i = 0; i < 4; ++i)
            a[i] = *(const short8v*)&As[cur][(wm * 64 + i * 16 + (lane & 15)) * 32 + (lane >> 4) * 8];
        #pragma unroll
        for (int j = 0; j < 4; ++j)
            b[j] = *(const short8v*)&Bs[cur][(wn * 64 + j * 16 + (lane & 15)) * 32 + (lane >> 4) * 8];
        #pragma unroll
        for (int i = 0; i < 4; ++i)
            #pragma unroll
            for (int j = 0; j < 4; ++j)
                acc[i][j] = __builtin_amdgcn_mfma_f32_16x16x32_bf16(a[i], b[j], acc[i][j], 0, 0, 0);
    }
    #pragma unroll
    for (int i = 0; i < 4; ++i) {
        const int rbase = m0 + wm * 64 + i * 16 + (lane >> 4) * 4;
        #pragma unroll
        for (int j = 0; j < 4; ++j) {
            const int col = n0 + wn * 64 + j * 16 + (lane & 15);
            if (col < Nreal) {
                #pragma unroll
                for (int r = 0; r < 4; ++r) {
                    if constexpr (BF16OUT)
                        ((ushort_t*)Cv)[(size_t)(rbase + r) * Nreal + col] = f2bf(acc[i][j][r]);
                    else
                        ((float*)Cv)[(size_t)(rbase + r) * Nreal + col] = acc[i][j][r];
                }
            }
        }
    }
}

// ---------------- gemm2 MFMA (BK=32, 32 KB LDS): per-k grouped GEMM, fused val*silu(gate) ----------------
__launch_bounds__(256)
__global__ void gemm2_mfma(const ushort_t* __restrict__ OCNb, const ushort_t* __restrict__ CskB,
                           const ushort_t* __restrict__ Btv, const ushort_t* __restrict__ Btg,
                           ushort_t* __restrict__ Y) {
    __shared__ ushort_t As[2][128 * 32];
    __shared__ ushort_t Bvs[2][64 * 32];
    __shared__ ushort_t Bgs[2][64 * 32];
    const int tid = threadIdx.x;
    const int lane = tid & 63, w = tid >> 6;
    const int m0 = blockIdx.x * 128;
    const int n0 = blockIdx.y * 64;
    const int k  = blockIdx.z;
    const int wm = w & 1, wn = w >> 1;
    const int lrow = lane >> 2;          // 0..15
    const int lcol = (lane & 3) * 8;     // 0,8,16,24
    const ushort_t* btv = Btv + (size_t)k * 192 * 320;
    const ushort_t* btg = Btg + (size_t)k * 192 * 320;

    f32x4 accV[4][2] = {};
    f32x4 accG[4][2] = {};

    auto stage = [&](int buf, int kt) {
        #pragma unroll
        for (int i = 0; i < 2; ++i) {
            const int seg = w * 2 + i;               // 0..7 (16 rows each)
            const int row = seg * 16 + lrow;         // 0..127
            const ushort_t* src = (kt < 4)
                ? OCNb + (size_t)(m0 + row) * DGATE + k * 128 + kt * 32 + lcol
                : CskB + (size_t)(m0 + row) * DIM_SKIP + (kt - 4) * 32 + lcol;
            gload_lds16(src, &As[buf][seg * 512]);
        }
        {
            const int seg = w;                       // 0..3 (16 rows each)
            const int row = seg * 16 + lrow;         // 0..63
            gload_lds16(btv + (size_t)(n0 + row) * 320 + kt * 32 + lcol, &Bvs[buf][seg * 512]);
            gload_lds16(btg + (size_t)(n0 + row) * 320 + kt * 32 + lcol, &Bgs[buf][seg * 512]);
        }
    };

    stage(0, 0);
    for (int kt = 0; kt < 10; ++kt) {
        const int cur = kt & 1;
        __syncthreads();
        if (kt + 1 < 10) stage(cur ^ 1, kt + 1);
        short8v a[4], bv[2], bg[2];
        #pragma unroll
        for (int i = 0; i < 4; ++i)
            a[i] = *(const short8v*)&As[cur][(wm * 64 + i * 16 + (lane & 15)) * 32 + (lane >> 4) * 8];
        #pragma unroll
        for (int j = 0; j < 2; ++j) {
            bv[j] = *(const short8v*)&Bvs[cur][(wn * 32 + j * 16 + (lane & 15)) * 32 + (lane >> 4) * 8];
            bg[j] = *(const short8v*)&Bgs[cur][(wn * 32 + j * 16 + (lane & 15)) * 32 + (lane >> 4) * 8];
        }
        #pragma unroll
        for (int i = 0; i < 4; ++i)
            #pragma unroll
            for (int j = 0; j < 2; ++j) {
                accV[i][j] = __builtin_amdgcn_mfma_f32_16x16x32_bf16(a[i], bv[j], accV[i][j], 0, 0, 0);
                accG[i][j] = __builtin_amdgcn_mfma_f32_16x16x32_bf16(a[i], bg[j], accG[i][j], 0, 0, 0);
            }
    }
    #pragma unroll
    for (int i = 0; i < 4; ++i) {
        const int rbase = m0 + wm * 64 + i * 16 + (lane >> 4) * 4;
        #pragma unroll
        for (int j = 0; j < 2; ++j) {
            const int col = k * 192 + n0 + wn * 32 + j * 16 + (lane & 15);
            #pragma unroll
            for (int r = 0; r < 4; ++r) {
                const float g = accG[i][j][r];
                Y[(size_t)(rbase + r) * (KK * 3 * HH) + col] = f2bf(accV[i][j][r] * (g * sigm(g)));
            }
        }
    }
}

// ---------------- fused feature + scan: per (b,k,chunk32), 64 lanes = 64 heads ----------------
// acc PACKED bf16x2 (uint32), token-major: accP[(b*LL+t)*KK + k][h]; pcum[(b*LL+t)*KK + k].
// Scan recursion + chunk carries (cend/cp) stay f32-exact; only stored outputs round.
__launch_bounds__(64)
__global__ void feat_scan(const ushort_t* __restrict__ Zb, const float* __restrict__ conv_w,
                          const float* __restrict__ wk, const float* __restrict__ theta_raw,
                          const float* __restrict__ dt_scale, const float* __restrict__ dt_bias,
                          const float* __restrict__ log_A, const float* __restrict__ phase_scale,
                          uint32_t* __restrict__ accP, float* __restrict__ pcum,
                          float2* __restrict__ cend, float* __restrict__ cp) {
    const int blk = blockIdx.x;                  // (b*KK+k)*NCHUNK + chunk
    const int bk = blk / NCHUNK, chunk = blk - bk * NCHUNK;
    const int b = bk / KK, k = bk - b * KK;
    const int h = threadIdx.x;
    const int t0 = chunk * LCHUNK;
    const int cm_ch = k * HH + h;
    const int cs_ch = DIM_MEM + k;

    const float w0 = conv_w[0 * DIM_CONV + cm_ch];
    const float w1 = conv_w[1 * DIM_CONV + cm_ch];
    const float w2 = conv_w[2 * DIM_CONV + cm_ch];
    const float w3 = conv_w[3 * DIM_CONV + cm_ch];
    const float s0 = conv_w[0 * DIM_CONV + cs_ch];
    const float s1 = conv_w[1 * DIM_CONV + cs_ch];
    const float s2 = conv_w[2 * DIM_CONV + cs_ch];
    const float s3 = conv_w[3 * DIM_CONV + cs_ch];
    const float wkh = wk[h];
    const float th = 0.001f + (3.0f - 0.001f) * sigm(theta_raw[cm_ch]);
    const float ps = phase_scale[k];
    const float dts = dt_scale[k], dtb = dt_bias[k];
    const float eA = expf(log_A[k]);

    const size_t rowb = (size_t)b * LL;
    auto zm_at = [&](int t) -> float {
        return (t >= 0) ? bf2f(Zb[(rowb + t) * DIM_TOTAL + cm_ch]) : 0.f;
    };
    auto zs_at = [&](int t) -> float {
        return (t >= 0) ? bf2f(Zb[(rowb + t) * DIM_TOTAL + cs_ch]) : 0.f;
    };
    float zm3 = zm_at(t0 - 3), zm2 = zm_at(t0 - 2), zm1 = zm_at(t0 - 1);
    float zs3 = zs_at(t0 - 3), zs2 = zs_at(t0 - 2), zs1 = zs_at(t0 - 1);

    float are = 0.f, aim = 0.f, P = 1.f;
    #pragma unroll 4
    for (int tt = 0; tt < LCHUNK; ++tt) {
        const int t = t0 + tt;
        const float zm0 = bf2f(Zb[(rowb + t) * DIM_TOTAL + cm_ch]);
        const float zs0 = bf2f(Zb[(rowb + t) * DIM_TOTAL + cs_ch]);
        float cm = fmaf(w0, zm3, fmaf(w1, zm2, fmaf(w2, zm1, w3 * zm0)));
        float cs = fmaf(s0, zs3, fmaf(s1, zs2, fmaf(s2, zs1, s3 * zs0)));
        const float um = cm * sigm(cm);
        const float us = cs * sigm(cs);
        float ssq = um * um;
        #pragma unroll
        for (int off = 32; off > 0; off >>= 1) ssq += __shfl_xor(ssq, off);
        const float kval = um * rsqrtf(ssq * (1.0f / (float)HH) + 1e-6f) * wkh;
        float lin = fminf(fmaxf(fmaf(dts, us, dtb), -20.f), 20.f);
        float dt = fminf(fmaxf(softplus_fast(lin), 0.001f), 0.1f);
        const float Ad = fminf(fmaxf(-eA * dt, -20.f), 0.f);
        const float dec = __expf(Ad);
        const float ks = kval * ps;
        const float phi = ks / (1.0f + fabsf(ks)) * th;
        const float kvw = kval * dt;
        float sp, cq;
        __sincosf(phi, &sp, &cq);
        are = fmaf(dec, are, kvw * cq);
        aim = fmaf(dec, aim, kvw * sp);
        P *= dec;
        const size_t tokK = (rowb + t) * KK + k;
        accP[tokK * HH + h] = (uint32_t)f2bf(are) | ((uint32_t)f2bf(aim) << 16);
        if (h == 0) pcum[tokK] = P;
        zm3 = zm2; zm2 = zm1; zm1 = zm0;
        zs3 = zs2; zs2 = zs1; zs1 = zs0;
    }
    cend[(size_t)blk * HH + h] = make_float2(are, aim);
    if (h == 0) cp[blk] = P;
}

// ---------------- scan phase B ----------------
__launch_bounds__(128)
__global__ void scan_b(const float* __restrict__ cend, const float* __restrict__ cp,
                       float* __restrict__ carry) {
    const int bk = blockIdx.x;
    const int c = threadIdx.x;
    float cur = 0.f;
    for (int ch = 0; ch < NCHUNK; ++ch) {
        const size_t idx = (size_t)bk * NCHUNK + ch;
        carry[idx * 128 + c] = cur;
        cur = fmaf(cp[idx], cur, cend[idx * 128 + c]);
    }
}

// ---------------- combine (slim): q-conv+rms, fixup, q-match, sigG apply, rms ----------------
__launch_bounds__(256)
__global__ void combine_kernel(const uint32_t* __restrict__ accP, const float* __restrict__ pcum,
                               const float2* __restrict__ carry, const ushort_t* __restrict__ Zb,
                               const float* __restrict__ conv_w, const float* __restrict__ wq,
                               const float* __restrict__ wintG, const ushort_t* sigG,
                               const float* __restrict__ gn_weight,
                               ushort_t* ocnB, ushort_t* __restrict__ cskB) {
    __shared__ float q_sh[DIM_Q];
    __shared__ float g_sh[DGATE];
    __shared__ float red[8];
    const int tok = blockIdx.x;
    const int b = tok / LL, t = tok % LL;
    const int tid = threadIdx.x;
    const int chunk = t / LCHUNK;
    const size_t zrow = (size_t)tok * DIM_TOTAL;
    const size_t tokK = (size_t)tok * KK;

    if (tid < DIM_SKIP) cskB[(size_t)tok * DIM_SKIP + tid] = Zb[zrow + DIM_CONV + tid];

    float part = 0.f;
    float qv[3];
    #pragma unroll
    for (int it = 0; it < 3; ++it) {
        const int c = tid + it * 256;
        const int ch = DIM_MEMT + c;
        float s = 0.f;
        #pragma unroll
        for (int j = 0; j < KSZ; ++j) {
            const int tt2 = t + j - (KSZ - 1);
            if (tt2 >= 0)
                s = fmaf(conv_w[j * DIM_CONV + ch],
                         bf2f(Zb[((size_t)(b * LL + tt2)) * DIM_TOTAL + ch]), s);
        }
        const float u = s * sigm(s);
        qv[it] = u;
        part = fmaf(u, u, part);
    }
    const float qss = blockReduceSum256(part, red);
    const float qrs = rsqrtf(qss / (float)DIM_Q + 1e-6f);
    #pragma unroll
    for (int it = 0; it < 3; ++it) {
        const int c = tid + it * 256;
        q_sh[c] = qv[it] * qrs * wq[c];
    }
    __syncthreads();

    float part2 = 0.f;
    #pragma unroll
    for (int it = 0; it < 3; ++it) {
        const int p = tid + it * 256;        // p = k*64 + h -> accP[tokK*768 + p] contiguous
        const int k = p >> 6, h = p & 63;
        const int kq = k >> 1;
        const float pc = pcum[tokK + k];
        const uint32_t ap = accP[tokK * HH + p];
        const float2 c2 = carry[((size_t)(b * KK + k) * NCHUNK + chunk) * HH + h];
        const float re = fmaf(pc, c2.x, bf2f((ushort_t)(ap & 0xffffu)));
        const float im = fmaf(pc, c2.y, bf2f((ushort_t)(ap >> 16)));
        const float qre = q_sh[kq * 128 + 2 * h];
        const float qim = q_sh[kq * 128 + 2 * h + 1];
        const float wint = wintG[p];
        const float ore = (re * qre + im * qim) * wint;
        const float oim = (im * qre - re * qim) * wint;
        const int cre = k * 128 + h, cim = k * 128 + 64 + h;
        const float g_re = ore * bf2f(sigG[(size_t)tok * DGATE + cre]);
        const float g_im = oim * bf2f(sigG[(size_t)tok * DGATE + cim]);
        g_sh[cre] = g_re;
        g_sh[cim] = g_im;
        part2 = fmaf(g_re, g_re, part2);
        part2 = fmaf(g_im, g_im, part2);
    }
    const float ss = blockReduceSum256(part2, red);   // barrier: all sigG reads done
    const float rs = rsqrtf(ss / (float)DGATE + 1e-6f);
    __syncthreads();
    #pragma unroll
    for (int it = 0; it < 6; ++it) {
        const int c = tid + it * 256;
        ocnB[(size_t)tok * DGATE + c] = f2bf(g_sh[c] * rs * gn_weight[c]);
    }
}

// ---------------- launch ----------------
static inline size_t pass_need_bytes(int TP) {
    const size_t BP = (size_t)TP / LL;
    size_t total = 0;
    total += (size_t)TP * DIM_TOTAL * 2;            // Zb bf16 (Y aliases Zb+acc start)
    total += (size_t)TP * KK * HH * 4;              // accP packed bf16x2
    total += (size_t)TP * KK * 4;                   // pcum
    total += BP * KK * NCHUNK * HH * 8;             // cend
    total += BP * KK * NCHUNK * 4;                  // cp
    total += BP * KK * NCHUNK * HH * 8;             // carry
    total += (size_t)TP * (DGATE + DIM_SKIP) * 2;   // ocnB(=sigG) + cskB (aliases xb)
    total += 8ull * 1024 * 1024;                    // WoutT + Btv + Btg + wint
    return total;
}

extern "C" void kernel_launch(void* const* d_in, const int* in_sizes, int n_in,
                              void* d_out, int out_size, void* d_ws, size_t ws_size,
                              hipStream_t stream) {
    const float* x           = (const float*)d_in[0];
    const float* W_in        = (const float*)d_in[1];
    const float* conv_w      = (const float*)d_in[2];
    const float* wk          = (const float*)d_in[3];
    const float* wq          = (const float*)d_in[4];
    const float* theta_raw   = (const float*)d_in[5];
    const float* w_int_raw   = (const float*)d_in[6];
    const float* dt_scale    = (const float*)d_in[7];
    const float* dt_bias     = (const float*)d_in[8];
    const float* log_A       = (const float*)d_in[9];
    const float* phase_scale = (const float*)d_in[10];
    const float* W_gate      = (const float*)d_in[11];
    const float* gn_weight   = (const float*)d_in[12];
    const float* W_readout   = (const float*)d_in[13];
    const float* W_skip      = (const float*)d_in[14];
    const float* W_out       = (const float*)d_in[15];
    float* out = (float*)d_out;

    int passes = 4;
    if (ws_size >= pass_need_bytes(TTOK))        passes = 1;
    else if (ws_size >= pass_need_bytes(TTOK/2)) passes = 2;

    const int BP = BB / passes;
    const int TP = BP * LL;

    char* p = (char*)d_ws;
    char* wsb = p;
    ushort_t* Zb   = (ushort_t*)p;               p += (size_t)TP * DIM_TOTAL * 2;
    char* accR     = p;
    uint32_t* accP = (uint32_t*)p;               p += (size_t)TP * KK * HH * 4;
    float* pcum    = (float*)p;                  p += (size_t)TP * KK * 4;
    float2* cendv  = (float2*)p;                 p += (size_t)BP * KK * NCHUNK * HH * 8;
    float* cp      = (float*)p;                  p += (size_t)BP * KK * NCHUNK * 4;
    float2* carry  = (float2*)p;                 p += (size_t)BP * KK * NCHUNK * HH * 8;
    char* ocnR     = p;
    ushort_t* ocnB = (ushort_t*)p;               p += (size_t)TP * DGATE * 2;
    ushort_t* cskB = (ushort_t*)p;               p += (size_t)TP * DIM_SKIP * 2;
    ushort_t* WoutT= (ushort_t*)p;               p += (size_t)768 * 2304 * 2;
    ushort_t* Btv  = (ushort_t*)p;               p += (size_t)KK * 192 * 320 * 2;
    ushort_t* Btg  = (ushort_t*)p;               p += (size_t)KK * 192 * 320 * 2;
    float* wintG   = (float*)p;                  p += (size_t)KK * HH * 4;
    // aliases (stream-serial lifetime reuse):
    ushort_t* xb   = (ushort_t*)ocnR;   // [TP][768] bf16, dead after GEMM1
    ushort_t* WinT = (ushort_t*)accR;   // [1792][768] bf16 (2.75 MB), dead after GEMM1
    ushort_t* Y    = (ushort_t*)wsb;    // [TP][2304] bf16 (75.5 MB) over Zb(57.5)+accP(18);
                                        // Zb & accP dead after combine; Y written by gemm2, read by GEMM3
    ushort_t* sigG = ocnB;              // gate sigmoids; consumed by combine BEFORE ocnB writes

    for (int pass = 0; pass < passes; ++pass) {
        const float* xp = x   + (size_t)pass * TP * DD;
        float*       op = out + (size_t)pass * TP * DD;

        // input-only preps (front-loaded)
        cast_bf16<<<1024, 256, 0, stream>>>(xp, xb, TP * DD / 4);
        transpose_cast<<<dim3(N1PAD / 32, DD / 32), dim3(32, 8), 0, stream>>>(
            W_in, WinT, DD, N1REAL, N1PAD);
        transpose_cast<<<dim3(DD / 32, (KK * 3 * HH) / 32), dim3(32, 8), 0, stream>>>(
            W_out, WoutT, KK * 3 * HH, DD, DD);
        prep_bt<<<dim3(KK, 192), 320, 0, stream>>>(W_readout, W_skip, Btv, Btg);
        prep_wint<<<3, 256, 0, stream>>>(w_int_raw, wintG);

        // 1. Zb = x @ W_in  (bf16 MFMA, bf16 output)
        mfma_gemm<true><<<dim3(TP / 128, N1PAD / 128), 256, 0, stream>>>(xb, WinT, Zb, N1REAL, DD);

        // 1b. sigG = sigmoid(gate_logits @ W_gate)
        gate_gemm16<<<TP / 16, 256, 0, stream>>>(Zb, W_gate, sigG);

        // 2. fused conv+feat+scan (packed bf16 acc, token-major)
        feat_scan<<<BP * KK * NCHUNK, 64, 0, stream>>>(Zb, conv_w, wk, theta_raw, dt_scale,
                                                       dt_bias, log_A, phase_scale,
                                                       accP, pcum, cendv, cp);

        // 3. carry propagation (f32-exact)
        scan_b<<<BP * KK, 128, 0, stream>>>((const float*)cendv, cp, (float*)carry);

        // 4. combine (reads sigG, then overwrites same region as ocnB)
        combine_kernel<<<TP, 256, 0, stream>>>(accP, pcum, carry, Zb, conv_w, wq, wintG,
                                               sigG, gn_weight, ocnB, cskB);

        // 5. Y(bf16) = val*silu(gate) of grouped MFMA GEMM (K=320, BK=32) — Y overwrites Zb/acc
        gemm2_mfma<<<dim3(TP / 128, 3, KK), 256, 0, stream>>>(ocnB, cskB, Btv, Btg, Y);

        // 6. out = Y @ W_out  (bf16 MFMA, f32 output)
        mfma_gemm<false><<<dim3(TP / 128, DD / 128), 256, 0, stream>>>(Y, WoutT, op, DD, KK * 3 * HH);
    }
}